// Round 12
// baseline (258.800 us; speedup 1.0000x reference)
//
#include <hip/hip_runtime.h>
#include <hip/hip_bf16.h>
#include <math.h>

#define NB 8        // batch
#define LNN 64      // nodes
#define LTN 256     // text len
#define DD 1024     // model dim
#define NH 4        // heads (each full width D)
#define HDD 4096    // NH*DD
#define DINN 2048
#define DHN 1024    // DIN/2

// 2*log2(e): tanh(x) = 1 - 2/(exp2(x*C)+1)
#define C_TANH 2.8853900817779268f

typedef __bf16 bf16x8 __attribute__((ext_vector_type(8)));
typedef float f32x4 __attribute__((ext_vector_type(4)));

__device__ __forceinline__ ushort f2b(float f) {
  unsigned int u = __builtin_bit_cast(unsigned int, f);
  u = (u + 0x7FFFu + ((u >> 16) & 1u)) >> 16;
  return (ushort)u;
}

// ---------------- mega-prep: activations cvt + all 6 weight transposes, 1 launch ----------------
__global__ __launch_bounds__(256) void prep(const float* __restrict__ node,
                                            ushort* __restrict__ node_bf,
                                            const float* __restrict__ text,
                                            ushort* __restrict__ text_bf,
                                            const float* __restrict__ Wq,
                                            const float* __restrict__ Wk,
                                            const float* __restrict__ Wv,
                                            const float* __restrict__ Wo,
                                            const float* __restrict__ aqW,
                                            const float* __restrict__ akW,
                                            ushort* __restrict__ TwtQKV,
                                            ushort* __restrict__ TwtWo,
                                            ushort* __restrict__ TwtAQ) {
  int bid = blockIdx.x;
  int t = threadIdx.x;
  if (bid < 1280) {
    const float* in;
    ushort* out;
    int i;
    if (bid < 256) { in = node; out = node_bf; i = (bid * 256 + t) * 8; }
    else { in = text; out = text_bf; i = ((bid - 256) * 256 + t) * 8; }
    float4 a = *(const float4*)(in + i);
    float4 b = *(const float4*)(in + i + 4);
    ushort4 o0 = {f2b(a.x), f2b(a.y), f2b(a.z), f2b(a.w)};
    ushort4 o1 = {f2b(b.x), f2b(b.y), f2b(b.z), f2b(b.w)};
    *(ushort4*)(out + i) = o0;
    *(ushort4*)(out + i + 4) = o1;
    return;
  }
  bid -= 1280;
  const float* W;
  ushort* dst0;
  int K, N, tt;
  if (bid < 3072) {
    int z = bid >> 10;
    tt = bid & 1023;
    W = (z == 0) ? Wq : ((z == 1) ? Wk : Wv);
    dst0 = TwtQKV + (size_t)z * DD * HDD;
    K = DD; N = HDD;
  } else if (bid < 4096) {
    tt = bid - 3072; W = Wo; dst0 = TwtWo; K = HDD; N = DD;
  } else if (bid < 4352) {
    tt = bid - 4096; W = aqW; dst0 = TwtAQ; K = DD; N = DD;
  } else {
    tt = bid - 4352; W = akW; dst0 = TwtAQ + (size_t)DD * DD; K = DD; N = DD;
  }
  int ntn = N >> 6;
  int n0 = (tt % ntn) << 6, k0 = (tt / ntn) << 6;
  __shared__ float tf[64][65];
  int r = t >> 2, c4 = (t & 3) * 16;
  const float* src = W + (size_t)(k0 + r) * N + n0 + c4;
  float4 v0 = *(const float4*)(src);
  float4 v1 = *(const float4*)(src + 4);
  float4 v2 = *(const float4*)(src + 8);
  float4 v3 = *(const float4*)(src + 12);
  *(float4*)&tf[r][c4] = v0;
  *(float4*)&tf[r][c4 + 4] = v1;
  *(float4*)&tf[r][c4 + 8] = v2;
  *(float4*)&tf[r][c4 + 12] = v3;
  __syncthreads();
  int nl = t >> 2, kc = (t & 3) * 16;
  ushort tmp[16];
#pragma unroll
  for (int j = 0; j < 16; ++j) tmp[j] = f2b(tf[kc + j][nl]);
  ushort* dst = dst0 + (size_t)(n0 + nl) * K + k0 + kc;
  *(uint4*)(dst) = *(uint4*)&tmp[0];
  *(uint4*)(dst + 8) = *(uint4*)&tmp[8];
}

// ---------------- QKV gemm (3 via grid.z): 64x128 tile, bf16 out, +bias ----------------
__global__ __launch_bounds__(256) void gemm_qkv3(const ushort* __restrict__ A,
                                                 const ushort* __restrict__ BtB,
                                                 const float* __restrict__ b0,
                                                 const float* __restrict__ b1,
                                                 const float* __restrict__ b2,
                                                 ushort* __restrict__ o0,
                                                 ushort* __restrict__ o1,
                                                 ushort* __restrict__ o2,
                                                 int M, int N, int K) {
  int z = blockIdx.z;
  const ushort* Bt = BtB + (size_t)z * N * K;
  const float* bias = (z == 0) ? b0 : ((z == 1) ? b1 : b2);
  ushort* Cout = (z == 0) ? o0 : ((z == 1) ? o1 : o2);
  __shared__ ushort Als[64 * 64];
  __shared__ ushort Bls[128 * 64];
  int tid = threadIdx.x;
  int m0 = blockIdx.y << 6, n0 = blockIdx.x << 7;
  int srow = tid >> 3, su = tid & 7;
  int sx = (su ^ (srow & 7)) * 8;
  const ushort* ga = A + (size_t)(m0 + srow) * K + su * 8;
  const ushort* gb = Bt + (size_t)(n0 + srow) * K + su * 8;
  int wa0 = srow * 64 + sx, wa1 = (srow + 32) * 64 + sx;
  int wb2 = (srow + 64) * 64 + sx, wb3 = (srow + 96) * 64 + sx;
  const size_t rs32 = (size_t)32 * K;
  int lane = tid & 63, w = tid >> 6;
  int wm = w >> 1, wn = w & 1;
  int r = lane & 15, kg = lane >> 4;
  f32x4 acc[2][4] = {};
  uint4 pa0 = *(const uint4*)(ga);
  uint4 pa1 = *(const uint4*)(ga + rs32);
  uint4 pb0 = *(const uint4*)(gb);
  uint4 pb1 = *(const uint4*)(gb + rs32);
  uint4 pb2 = *(const uint4*)(gb + 2 * rs32);
  uint4 pb3 = *(const uint4*)(gb + 3 * rs32);
  for (int k0 = 0; k0 < K; k0 += 64) {
    __syncthreads();
    *(uint4*)&Als[wa0] = pa0; *(uint4*)&Als[wa1] = pa1;
    *(uint4*)&Bls[wa0] = pb0; *(uint4*)&Bls[wa1] = pb1;
    *(uint4*)&Bls[wb2] = pb2; *(uint4*)&Bls[wb3] = pb3;
    __syncthreads();
    int kn = k0 + 64;
    if (kn < K) {
      pa0 = *(const uint4*)(ga + kn);
      pa1 = *(const uint4*)(ga + rs32 + kn);
      pb0 = *(const uint4*)(gb + kn);
      pb1 = *(const uint4*)(gb + rs32 + kn);
      pb2 = *(const uint4*)(gb + 2 * rs32 + kn);
      pb3 = *(const uint4*)(gb + 3 * rs32 + kn);
    }
#pragma unroll
    for (int h = 0; h < 2; ++h) {
      int sa = ((h * 4 + kg) ^ (r & 7)) * 8;
      bf16x8 af[2], bfr[4];
#pragma unroll
      for (int m = 0; m < 2; ++m)
        af[m] = *(const bf16x8*)&Als[(wm * 32 + m * 16 + r) * 64 + sa];
#pragma unroll
      for (int n = 0; n < 4; ++n)
        bfr[n] = *(const bf16x8*)&Bls[(wn * 64 + n * 16 + r) * 64 + sa];
#pragma unroll
      for (int m = 0; m < 2; ++m)
#pragma unroll
        for (int n = 0; n < 4; ++n)
          acc[m][n] = __builtin_amdgcn_mfma_f32_16x16x32_bf16(af[m], bfr[n], acc[m][n], 0, 0, 0);
    }
  }
#pragma unroll
  for (int m = 0; m < 2; ++m)
#pragma unroll
    for (int n = 0; n < 4; ++n) {
      f32x4 a = acc[m][n];
#pragma unroll
      for (int v = 0; v < 4; ++v) {
        int row = m0 + wm * 32 + m * 16 + kg * 4 + v;
        int col = n0 + wn * 64 + n * 16 + r;
        Cout[(size_t)row * N + col] = f2b(a[v] + bias[col]);
      }
    }
}

// ---------------- Wo gemm with split-K 4 (grid.z): fp32 partials ----------------
__global__ __launch_bounds__(256) void gemm_wo_split(const ushort* __restrict__ A,
                                                     const ushort* __restrict__ Bt,
                                                     float* __restrict__ P,
                                                     int M, int N, int K) {
  __shared__ ushort Als[64 * 64];
  __shared__ ushort Bls[128 * 64];
  int tid = threadIdx.x;
  int m0 = blockIdx.y << 6, n0 = blockIdx.x << 7;
  int Ks = K >> 2, kbase = blockIdx.z * Ks;
  int srow = tid >> 3, su = tid & 7;
  int sx = (su ^ (srow & 7)) * 8;
  const ushort* ga = A + (size_t)(m0 + srow) * K + kbase + su * 8;
  const ushort* gb = Bt + (size_t)(n0 + srow) * K + kbase + su * 8;
  int wa0 = srow * 64 + sx, wa1 = (srow + 32) * 64 + sx;
  int wb2 = (srow + 64) * 64 + sx, wb3 = (srow + 96) * 64 + sx;
  const size_t rs32 = (size_t)32 * K;
  int lane = tid & 63, w = tid >> 6;
  int wm = w >> 1, wn = w & 1;
  int r = lane & 15, kg = lane >> 4;
  f32x4 acc[2][4] = {};
  uint4 pa0 = *(const uint4*)(ga);
  uint4 pa1 = *(const uint4*)(ga + rs32);
  uint4 pb0 = *(const uint4*)(gb);
  uint4 pb1 = *(const uint4*)(gb + rs32);
  uint4 pb2 = *(const uint4*)(gb + 2 * rs32);
  uint4 pb3 = *(const uint4*)(gb + 3 * rs32);
  for (int k0 = 0; k0 < Ks; k0 += 64) {
    __syncthreads();
    *(uint4*)&Als[wa0] = pa0; *(uint4*)&Als[wa1] = pa1;
    *(uint4*)&Bls[wa0] = pb0; *(uint4*)&Bls[wa1] = pb1;
    *(uint4*)&Bls[wb2] = pb2; *(uint4*)&Bls[wb3] = pb3;
    __syncthreads();
    int kn = k0 + 64;
    if (kn < Ks) {
      pa0 = *(const uint4*)(ga + kn);
      pa1 = *(const uint4*)(ga + rs32 + kn);
      pb0 = *(const uint4*)(gb + kn);
      pb1 = *(const uint4*)(gb + rs32 + kn);
      pb2 = *(const uint4*)(gb + 2 * rs32 + kn);
      pb3 = *(const uint4*)(gb + 3 * rs32 + kn);
    }
#pragma unroll
    for (int h = 0; h < 2; ++h) {
      int sa = ((h * 4 + kg) ^ (r & 7)) * 8;
      bf16x8 af[2], bfr[4];
#pragma unroll
      for (int m = 0; m < 2; ++m)
        af[m] = *(const bf16x8*)&Als[(wm * 32 + m * 16 + r) * 64 + sa];
#pragma unroll
      for (int n = 0; n < 4; ++n)
        bfr[n] = *(const bf16x8*)&Bls[(wn * 64 + n * 16 + r) * 64 + sa];
#pragma unroll
      for (int m = 0; m < 2; ++m)
#pragma unroll
        for (int n = 0; n < 4; ++n)
          acc[m][n] = __builtin_amdgcn_mfma_f32_16x16x32_bf16(af[m], bfr[n], acc[m][n], 0, 0, 0);
    }
  }
#pragma unroll
  for (int m = 0; m < 2; ++m)
#pragma unroll
    for (int n = 0; n < 4; ++n) {
      f32x4 a = acc[m][n];
#pragma unroll
      for (int v = 0; v < 4; ++v) {
        int row = m0 + wm * 32 + m * 16 + kg * 4 + v;
        int col = n0 + wn * 64 + n * 16 + r;
        P[((size_t)blockIdx.z * M + row) * N + col] = a[v];
      }
    }
}

// ---------------- aq+ak gemm (M-concat row select): fp32 out, *C_TANH ----------------
__global__ __launch_bounds__(256) void gemm_aqak(const ushort* __restrict__ H2,
                                                 const ushort* __restrict__ Tbf,
                                                 const ushort* __restrict__ TwtAQ,
                                                 const float* __restrict__ aqb,
                                                 const float* __restrict__ akb,
                                                 const float* __restrict__ attb,
                                                 float* __restrict__ QBu,
                                                 float* __restrict__ KAB,
                                                 int N, int K) {
  __shared__ ushort Als[64 * 64];
  __shared__ ushort Bls[128 * 64];
  int tid = threadIdx.x;
  int gm0 = blockIdx.y << 6, n0 = blockIdx.x << 7;
  const ushort* Abase;
  const ushort* Bt;
  const float* bias;
  const float* bias2;
  float* Obase;
  if (gm0 < 512) {
    Abase = H2 + (size_t)gm0 * K;
    Bt = TwtAQ;
    bias = aqb; bias2 = nullptr;
    Obase = QBu + (size_t)gm0 * N;
  } else {
    Abase = Tbf + (size_t)(gm0 - 512) * K;
    Bt = TwtAQ + (size_t)N * K;
    bias = akb; bias2 = attb;
    Obase = KAB + (size_t)(gm0 - 512) * N;
  }
  int srow = tid >> 3, su = tid & 7;
  int sx = (su ^ (srow & 7)) * 8;
  const ushort* ga = Abase + (size_t)srow * K + su * 8;
  const ushort* gb = Bt + (size_t)(n0 + srow) * K + su * 8;
  int wa0 = srow * 64 + sx, wa1 = (srow + 32) * 64 + sx;
  int wb2 = (srow + 64) * 64 + sx, wb3 = (srow + 96) * 64 + sx;
  const size_t rs32 = (size_t)32 * K;
  int lane = tid & 63, w = tid >> 6;
  int wm = w >> 1, wn = w & 1;
  int r = lane & 15, kg = lane >> 4;
  f32x4 acc[2][4] = {};
  uint4 pa0 = *(const uint4*)(ga);
  uint4 pa1 = *(const uint4*)(ga + rs32);
  uint4 pb0 = *(const uint4*)(gb);
  uint4 pb1 = *(const uint4*)(gb + rs32);
  uint4 pb2 = *(const uint4*)(gb + 2 * rs32);
  uint4 pb3 = *(const uint4*)(gb + 3 * rs32);
  for (int k0 = 0; k0 < K; k0 += 64) {
    __syncthreads();
    *(uint4*)&Als[wa0] = pa0; *(uint4*)&Als[wa1] = pa1;
    *(uint4*)&Bls[wa0] = pb0; *(uint4*)&Bls[wa1] = pb1;
    *(uint4*)&Bls[wb2] = pb2; *(uint4*)&Bls[wb3] = pb3;
    __syncthreads();
    int kn = k0 + 64;
    if (kn < K) {
      pa0 = *(const uint4*)(ga + kn);
      pa1 = *(const uint4*)(ga + rs32 + kn);
      pb0 = *(const uint4*)(gb + kn);
      pb1 = *(const uint4*)(gb + rs32 + kn);
      pb2 = *(const uint4*)(gb + 2 * rs32 + kn);
      pb3 = *(const uint4*)(gb + 3 * rs32 + kn);
    }
#pragma unroll
    for (int h = 0; h < 2; ++h) {
      int sa = ((h * 4 + kg) ^ (r & 7)) * 8;
      bf16x8 af[2], bfr[4];
#pragma unroll
      for (int m = 0; m < 2; ++m)
        af[m] = *(const bf16x8*)&Als[(wm * 32 + m * 16 + r) * 64 + sa];
#pragma unroll
      for (int n = 0; n < 4; ++n)
        bfr[n] = *(const bf16x8*)&Bls[(wn * 64 + n * 16 + r) * 64 + sa];
#pragma unroll
      for (int m = 0; m < 2; ++m)
#pragma unroll
        for (int n = 0; n < 4; ++n)
          acc[m][n] = __builtin_amdgcn_mfma_f32_16x16x32_bf16(af[m], bfr[n], acc[m][n], 0, 0, 0);
    }
  }
#pragma unroll
  for (int m = 0; m < 2; ++m)
#pragma unroll
    for (int n = 0; n < 4; ++n) {
      f32x4 a = acc[m][n];
#pragma unroll
      for (int v = 0; v < 4; ++v) {
        int lrow = wm * 32 + m * 16 + kg * 4 + v;
        int col = n0 + wn * 64 + n * 16 + r;
        float x = a[v] + bias[col];
        if (bias2) x += bias2[col];
        Obase[(size_t)lrow * N + col] = x * C_TANH;
      }
    }
}

// ---------------- Wo split-K(4) reduce + bias + residual + LayerNorm -> bf16 ----------------
__global__ __launch_bounds__(256) void wo_ln(const float* __restrict__ P,
                                             const float* __restrict__ bo,
                                             const float* __restrict__ node,
                                             const float* __restrict__ g,
                                             const float* __restrict__ be,
                                             ushort* __restrict__ Y) {
  int row = blockIdx.x, tid = threadIdx.x;
  int c = tid * 4;
  const size_t MN = (size_t)512 * 1024;
  size_t o = (size_t)row * DD + c;
  float4 v0 = *(const float4*)(P + o);
  float4 v1 = *(const float4*)(P + MN + o);
  float4 v2 = *(const float4*)(P + 2 * MN + o);
  float4 v3 = *(const float4*)(P + 3 * MN + o);
  float4 rv = *(const float4*)(node + o);
  float4 bv = *(const float4*)(bo + c);
  float4 v;
  v.x = v0.x + v1.x + v2.x + v3.x + rv.x + bv.x;
  v.y = v0.y + v1.y + v2.y + v3.y + rv.y + bv.y;
  v.z = v0.z + v1.z + v2.z + v3.z + rv.z + bv.z;
  v.w = v0.w + v1.w + v2.w + v3.w + rv.w + bv.w;
  float s = v.x + v.y + v.z + v.w;
  float ss = v.x * v.x + v.y * v.y + v.z * v.z + v.w * v.w;
  for (int o2 = 32; o2; o2 >>= 1) {
    s += __shfl_xor(s, o2, 64);
    ss += __shfl_xor(ss, o2, 64);
  }
  __shared__ float rb_[8];
  int lane = tid & 63, w = tid >> 6;
  if (lane == 0) { rb_[w] = s; rb_[4 + w] = ss; }
  __syncthreads();
  s = rb_[0] + rb_[1] + rb_[2] + rb_[3];
  ss = rb_[4] + rb_[5] + rb_[6] + rb_[7];
  float mu = s * (1.f / 1024.f);
  float var = ss * (1.f / 1024.f) - mu * mu;
  float rstd = rsqrtf(var + 1e-5f);
  ushort4 o4;
  o4.x = f2b((v.x - mu) * rstd * g[c + 0] + be[c + 0]);
  o4.y = f2b((v.y - mu) * rstd * g[c + 1] + be[c + 1]);
  o4.z = f2b((v.z - mu) * rstd * g[c + 2] + be[c + 2]);
  o4.w = f2b((v.w - mu) * rstd * g[c + 3] + be[c + 3]);
  *(ushort4*)(Y + (size_t)row * DD + c) = o4;
}

// ---------------- fused attention: per (bh, dtile) full QK^T + softmax + PV ----------------
// grid 256 = 32 bh x 8 dt. QK^T redundantly recomputed per dt (2.2 GFLOP total, < 1 launch gap).
__global__ __launch_bounds__(256) void attn_one(const ushort* __restrict__ Qb,
                                                const ushort* __restrict__ Kb,
                                                const ushort* __restrict__ Vb,
                                                const int* __restrict__ gmask,
                                                ushort* __restrict__ AO) {
  int bid = blockIdx.x;
  int bh = bid >> 3, dt = bid & 7;
  int b = bh >> 2;
  int d0 = dt * 128;
  size_t base = ((size_t)b * LNN) * HDD + (size_t)(bh & 3) * DD;
  __shared__ ushort Als[64 * 64];
  __shared__ ushort Bls[64 * 64];
  __shared__ float S[64][68];
  __shared__ ushort Pls[64 * 72];
  __shared__ ushort Vt[128 * 72];
  int tid = threadIdx.x;
  int lane = tid & 63, w = tid >> 6;
  int wm = w >> 1, wn = w & 1;
  int r = lane & 15, kg = lane >> 4;
  // ---- QK^T over full K = 1024 ----
  {
    int srow = tid >> 2, su0 = (tid & 3) * 2;
    const ushort* ga = Qb + base + (size_t)srow * HDD + su0 * 8;
    const ushort* gb = Kb + base + (size_t)srow * HDD + su0 * 8;
    int wa0 = srow * 64 + ((su0) ^ (srow & 7)) * 8;
    int wa1 = srow * 64 + ((su0 + 1) ^ (srow & 7)) * 8;
    f32x4 acc[2][2] = {};
    uint4 pa0 = *(const uint4*)(ga);
    uint4 pa1 = *(const uint4*)(ga + 8);
    uint4 pb0 = *(const uint4*)(gb);
    uint4 pb1 = *(const uint4*)(gb + 8);
    for (int k0 = 0; k0 < DD; k0 += 64) {
      __syncthreads();
      *(uint4*)&Als[wa0] = pa0; *(uint4*)&Als[wa1] = pa1;
      *(uint4*)&Bls[wa0] = pb0; *(uint4*)&Bls[wa1] = pb1;
      __syncthreads();
      int kn = k0 + 64;
      if (kn < DD) {
        pa0 = *(const uint4*)(ga + kn);
        pa1 = *(const uint4*)(ga + kn + 8);
        pb0 = *(const uint4*)(gb + kn);
        pb1 = *(const uint4*)(gb + kn + 8);
      }
#pragma unroll
      for (int h = 0; h < 2; ++h) {
        int sa = ((h * 4 + kg) ^ (r & 7)) * 8;
        bf16x8 af[2], bfr[2];
#pragma unroll
        for (int m = 0; m < 2; ++m)
          af[m] = *(const bf16x8*)&Als[(wm * 32 + m * 16 + r) * 64 + sa];
#pragma unroll
        for (int n = 0; n < 2; ++n)
          bfr[n] = *(const bf16x8*)&Bls[(wn * 32 + n * 16 + r) * 64 + sa];
#pragma unroll
        for (int m = 0; m < 2; ++m)
#pragma unroll
          for (int n = 0; n < 2; ++n)
            acc[m][n] = __builtin_amdgcn_mfma_f32_16x16x32_bf16(af[m], bfr[n], acc[m][n], 0, 0, 0);
      }
    }
#pragma unroll
    for (int m = 0; m < 2; ++m)
#pragma unroll
      for (int n = 0; n < 2; ++n)
#pragma unroll
        for (int v = 0; v < 4; ++v)
          S[wm * 32 + m * 16 + kg * 4 + v][wn * 32 + n * 16 + r] = acc[m][n][v];
  }
  // ---- stage V^T for this 128-d tile (independent of S) ----
  {
    int kq = lane, dq = w * 32;
    const ushort* src = Vb + base + (size_t)kq * HDD + d0 + dq;
    uint4 v0 = *(const uint4*)src;
    uint4 v1 = *(const uint4*)(src + 8);
    uint4 v2 = *(const uint4*)(src + 16);
    uint4 v3 = *(const uint4*)(src + 24);
    ushort tmp[32];
    *(uint4*)&tmp[0] = v0; *(uint4*)&tmp[8] = v1;
    *(uint4*)&tmp[16] = v2; *(uint4*)&tmp[24] = v3;
#pragma unroll
    for (int j = 0; j < 32; ++j) Vt[(dq + j) * 72 + kq] = tmp[j];
  }
  __syncthreads();
  // ---- masked softmax: wave w owns rows w*16..w*16+15, lane = k ----
  bool valid = gmask[b * LNN + lane] != 0;
  for (int i = 0; i < 16; ++i) {
    int q = w * 16 + i;
    float v = valid ? S[q][lane] * 0.03125f : -__builtin_inff();
    float mx = v;
    for (int o = 32; o; o >>= 1) mx = fmaxf(mx, __shfl_xor(mx, o, 64));
    float e = valid ? __expf(v - mx) : 0.f;
    float s = e;
    for (int o = 32; o; o >>= 1) s += __shfl_xor(s, o, 64);
    Pls[q * 72 + lane] = f2b(__fdividef(e, s));
  }
  __syncthreads();
  // ---- PV for the 128-wide d tile ----
  f32x4 acc[2][4] = {};
#pragma unroll
  for (int h = 0; h < 2; ++h) {
    int ko = h * 32 + kg * 8;
    bf16x8 af[2], bfr[4];
#pragma unroll
    for (int m = 0; m < 2; ++m)
      af[m] = *(const bf16x8*)&Pls[(wm * 32 + m * 16 + r) * 72 + ko];
#pragma unroll
    for (int n = 0; n < 4; ++n)
      bfr[n] = *(const bf16x8*)&Vt[(wn * 64 + n * 16 + r) * 72 + ko];
#pragma unroll
    for (int m = 0; m < 2; ++m)
#pragma unroll
      for (int n = 0; n < 4; ++n)
        acc[m][n] = __builtin_amdgcn_mfma_f32_16x16x32_bf16(af[m], bfr[n], acc[m][n], 0, 0, 0);
  }
#pragma unroll
  for (int m = 0; m < 2; ++m)
#pragma unroll
    for (int n = 0; n < 4; ++n) {
      f32x4 a = acc[m][n];
#pragma unroll
      for (int v = 0; v < 4; ++v) {
        int q = wm * 32 + m * 16 + kg * 4 + v;
        int col = wn * 64 + n * 16 + r;
        AO[base + (size_t)q * HDD + d0 + col] = f2b(a[v]);
      }
    }
}

// ---------------- additive attention phase 1: 8-q reuse, 128-d slices ----------------
__global__ __launch_bounds__(256) void addatt_e(const float* __restrict__ QBu,
                                                const float* __restrict__ KAB,
                                                const float* __restrict__ av_,
                                                float* __restrict__ E8) {
  int ds = blockIdx.x, qt = blockIdx.y, b = blockIdx.z;
  int tid = threadIdx.x;
  __shared__ float qs[8][128];
  __shared__ float avs[128];
  __shared__ float red[4];
  int bq0 = b * LNN + qt * 8;
  {
    int qq = tid >> 5, dd = (tid & 31) * 4;
    *(float4*)&qs[qq][dd] = *(const float4*)(QBu + (size_t)(bq0 + qq) * DD + ds * 128 + dd);
  }
  float av = (tid < 128) ? av_[ds * 128 + tid] : 0.f;
  if (tid < 128) avs[tid] = av;
  float s = av;
  for (int o = 32; o; o >>= 1) s += __shfl_xor(s, o, 64);
  int lane = tid & 63, w = tid >> 6;
  if (lane == 0) red[w] = s;
  __syncthreads();
  float sumav = red[0] + red[1] + red[2] + red[3];
  const float* kr = KAB + (size_t)(b * LTN + tid) * DD + ds * 128;
  float ac[8] = {};
#pragma unroll 2
  for (int d = 0; d < 128; d += 4) {
    float4 kv = *(const float4*)(kr + d);
    float4 av4 = *(const float4*)&avs[d];
#pragma unroll
    for (int qq = 0; qq < 8; ++qq) {
      float4 q4 = *(const float4*)&qs[qq][d];
      ac[qq] = fmaf(av4.x, __builtin_amdgcn_rcpf(__builtin_amdgcn_exp2f(q4.x + kv.x) + 1.f), ac[qq]);
      ac[qq] = fmaf(av4.y, __builtin_amdgcn_rcpf(__builtin_amdgcn_exp2f(q4.y + kv.y) + 1.f), ac[qq]);
      ac[qq] = fmaf(av4.z, __builtin_amdgcn_rcpf(__builtin_amdgcn_exp2f(q4.z + kv.z) + 1.f), ac[qq]);
      ac[qq] = fmaf(av4.w, __builtin_amdgcn_rcpf(__builtin_amdgcn_exp2f(q4.w + kv.w) + 1.f), ac[qq]);
    }
  }
  size_t ebase = ((size_t)ds * 512 + bq0) * LTN + tid;
#pragma unroll
  for (int qq = 0; qq < 8; ++qq)
    E8[ebase + (size_t)qq * LTN] = sumav - 2.f * ac[qq];
}

// ---------------- fused: sum partials + 64 masked softmaxes + pooled context ----------------
// grid (NB). Per block: coefficient vector cf[k] = sum_q m_q softmax_k(e[q,k]), then pool.
__global__ __launch_bounds__(256) void addatt_smpool(const float* __restrict__ E8,
                                                     const int* __restrict__ lmask,
                                                     const float* __restrict__ text,
                                                     const int* __restrict__ gmask,
                                                     float* __restrict__ H4) {
  int b = blockIdx.x;
  int tid = threadIdx.x;
  __shared__ float cf[LTN];
  __shared__ float rb_[8];
  int lane = tid & 63, w = tid >> 6;
  bool valid = lmask[b * LTN + tid] != 0;
  float cnt = 0.f;
#pragma unroll
  for (int q = 0; q < LNN; ++q) cnt += (gmask[b * LNN + q] != 0) ? 1.f : 0.f;
  cnt = fmaxf(cnt, 9.765625e-04f);
  float coeff = 0.f;
  for (int q = 0; q < LNN; ++q) {
    int bq = b * LNN + q;
    float e = 0.f;
#pragma unroll
    for (int ks = 0; ks < 8; ++ks)
      e += E8[((size_t)ks * 512 + bq) * LTN + tid];
    float v = valid ? e : -__builtin_inff();
    float m = v;
    for (int o = 32; o; o >>= 1) m = fmaxf(m, __shfl_xor(m, o, 64));
    if (lane == 0) rb_[w] = m;
    __syncthreads();
    m = fmaxf(fmaxf(rb_[0], rb_[1]), fmaxf(rb_[2], rb_[3]));
    float ex = valid ? __expf(v - m) : 0.f;
    float sm = ex;
    for (int o = 32; o; o >>= 1) sm += __shfl_xor(sm, o, 64);
    if (lane == 0) rb_[4 + w] = sm;
    __syncthreads();
    sm = rb_[4] + rb_[5] + rb_[6] + rb_[7];
    if (gmask[bq] != 0) coeff += __fdividef(ex, sm);
  }
  cf[tid] = coeff;
  __syncthreads();
  const float* tb = text + (size_t)b * LTN * DD;
#pragma unroll
  for (int dt = 0; dt < 4; ++dt) {
    int d = dt * 256 + tid;
    float acc = 0.f;
#pragma unroll 8
    for (int k = 0; k < LTN; ++k) acc = fmaf(cf[k], tb[(size_t)k * DD + d], acc);
    H4[b * DD + d] = acc / cnt;
  }
}

// ---------------- split-K GEMV (dp1) ----------------
__global__ __launch_bounds__(256) void dp_split(const float* __restrict__ X,
                                                const float* __restrict__ W,
                                                float* __restrict__ P,
                                                int K, int N) {
  int jt = blockIdx.x, kt = blockIdx.y;
  int t = threadIdx.x;
  __shared__ float xs[8][32];
  if (t < 64) {
    int b = t >> 3, kk = (t & 7) * 4;
    *(float4*)&xs[b][kk] = *(const float4*)(X + (size_t)b * K + kt * 32 + kk);
  }
  __syncthreads();
  int j = jt * 64 + (t & 63);
  int bg = (t >> 6) * 2;
  const float* wp = W + (size_t)(kt * 32) * N + j;
  float a0 = 0.f, a1 = 0.f;
#pragma unroll
  for (int k = 0; k < 32; ++k) {
    float w = wp[(size_t)k * N];
    a0 = fmaf(xs[bg + 0][k], w, a0);
    a1 = fmaf(xs[bg + 1][k], w, a1);
  }
  P[((size_t)kt * 8 + bg + 0) * N + j] = a0;
  P[((size_t)kt * 8 + bg + 1) * N + j] = a1;
}

// ---------------- dp2 split-K GEMV with inline dp1-reduce + GELU ----------------
__global__ __launch_bounds__(256) void dp_split2g(const float* __restrict__ P1,
                                                  const float* __restrict__ b1,
                                                  const float* __restrict__ W,
                                                  float* __restrict__ P,
                                                  int K, int N) {
  int jt = blockIdx.x, kt = blockIdx.y;
  int t = threadIdx.x;
  __shared__ float xs[8][32];
  {
    int b = t >> 5, kk = t & 31;
    int j = kt * 32 + kk;
    float s = b1[j];
#pragma unroll 8
    for (int p = 0; p < 32; ++p) s += P1[((size_t)p * 8 + b) * K + j];
    xs[b][kk] = 0.5f * s * (1.f + erff(s * 0.70710678118654752440f));
  }
  __syncthreads();
  int j = jt * 64 + (t & 63);
  int bg = (t >> 6) * 2;
  const float* wp = W + (size_t)(kt * 32) * N + j;
  float a0 = 0.f, a1 = 0.f;
#pragma unroll
  for (int k = 0; k < 32; ++k) {
    float w = wp[(size_t)k * N];
    a0 = fmaf(xs[bg + 0][k], w, a0);
    a1 = fmaf(xs[bg + 1][k], w, a1);
  }
  P[((size_t)kt * 8 + bg + 0) * N + j] = a0;
  P[((size_t)kt * 8 + bg + 1) * N + j] = a1;
}

template <int GELU>
__global__ __launch_bounds__(256) void dp_reduce(const float* __restrict__ P,
                                                 const float* __restrict__ bias,
                                                 float* __restrict__ O, int N) {
  int b = blockIdx.y;
  int j = blockIdx.x * 256 + threadIdx.x;
  float s = bias[j];
#pragma unroll 8
  for (int kt = 0; kt < 32; ++kt) s += P[((size_t)kt * 8 + b) * N + j];
  if constexpr (GELU) s = 0.5f * s * (1.f + erff(s * 0.70710678118654752440f));
  O[(size_t)b * N + j] = s;
}

extern "C" void kernel_launch(void* const* d_in, const int* in_sizes, int n_in,
                              void* d_out, int out_size, void* d_ws, size_t ws_size,
                              hipStream_t stream) {
  const float* text = (const float*)d_in[0];
  const float* node = (const float*)d_in[1];
  const float* Wq = (const float*)d_in[2];
  const float* bq = (const float*)d_in[3];
  const float* Wk = (const float*)d_in[4];
  const float* bk = (const float*)d_in[5];
  const float* Wv = (const float*)d_in[6];
  const float* bv = (const float*)d_in[7];
  const float* Wo = (const float*)d_in[8];
  const float* bo = (const float*)d_in[9];
  const float* lng = (const float*)d_in[10];
  const float* lnb = (const float*)d_in[11];
  const float* aqW = (const float*)d_in[12];
  const float* aqb = (const float*)d_in[13];
  const float* akW = (const float*)d_in[14];
  const float* akb = (const float*)d_in[15];
  const float* attv = (const float*)d_in[16];
  const float* attb = (const float*)d_in[17];
  const float* dp1W = (const float*)d_in[18];
  const float* dp1b = (const float*)d_in[19];
  const float* dp2W = (const float*)d_in[20];
  const float* dp2b = (const float*)d_in[21];
  const int* gmask = (const int*)d_in[22];
  const int* lmask = (const int*)d_in[23];
  (void)in_sizes; (void)n_in; (void)out_size; (void)ws_size;

  char* base = (char*)d_ws;
#define MB(x) (((size_t)(x)) << 20)
  ushort* TwtQKV = (ushort*)(base);                 // 0..24 MB
  ushort* TwtWo = (ushort*)(base + MB(24));         // 24..32
  ushort* TwtAQ = (ushort*)(base + MB(32));         // 32..36
  ushort* node_bf = (ushort*)(base + MB(36));       // 36..37
  ushort* text_bf = (ushort*)(base + MB(37));       // 37..41
  ushort* Qb = (ushort*)(base + MB(41));            // 41..45
  ushort* Kb = (ushort*)(base + MB(45));            // 45..49
  ushort* Vb = (ushort*)(base + MB(49));            // 49..53
  ushort* AO = (ushort*)(base + MB(53));            // 53..57
  float* P_Wo = (float*)(base + MB(61));            // 61..69 (4 slices x 2MB)
  ushort* H2 = (ushort*)(base + MB(69));            // 69..70
  float* QBu = (float*)(base + MB(70));             // 70..72
  float* KAB = (float*)(base + MB(72));             // 72..80
  float* E8 = (float*)(base + MB(80));              // 80..84
  float* H4 = (float*)(base + MB(84) + (512 << 10));   // 32KB
  float* P1 = (float*)(base + MB(85));              // 85..86
  float* P2 = (float*)(base + MB(86));              // 86..88
  float* Z = (float*)d_out;
#undef MB

  const int M1 = NB * LNN;  // 512
  dim3 blk(256);

  // one launch: activations cvt + all 6 weight transposes
  prep<<<dim3(5888), blk, 0, stream>>>(node, node_bf, text, text_bf,
                                       Wq, Wk, Wv, Wo, aqW, akW,
                                       TwtQKV, TwtWo, TwtAQ);

  // QKV projections (64x128 tiles, grid.z = 3)
  gemm_qkv3<<<dim3(HDD / 128, M1 / 64, 3), blk, 0, stream>>>(node_bf, TwtQKV, bq, bk, bv, Qb, Kb, Vb, M1, HDD, DD);

  // fused self-attention: QK^T (redundant per d-tile) + softmax + PV, 256 blocks
  attn_one<<<dim3(NB * NH * 8), blk, 0, stream>>>(Qb, Kb, Vb, gmask, AO);

  // output proj: split-K 4-way partials, then fused reduce+residual+LayerNorm
  gemm_wo_split<<<dim3(DD / 128, M1 / 64, 4), blk, 0, stream>>>(AO, TwtWo, P_Wo, M1, DD, HDD);
  wo_ln<<<dim3(M1), blk, 0, stream>>>(P_Wo, bo, node, lng, lnb, H2);

  // aq + ak (M-concat), outputs pre-scaled by C_TANH
  gemm_aqak<<<dim3(DD / 128, 40), blk, 0, stream>>>(H2, text_bf, TwtAQ, aqb, akb, attb, QBu, KAB, DD, DD);

  // additive attention: partial-e (8-q reuse, 8 d-slices) -> fused softmax+pool
  addatt_e<<<dim3(8, 8, NB), blk, 0, stream>>>(QBu, KAB, attv, E8);
  addatt_smpool<<<dim3(NB), blk, 0, stream>>>(E8, lmask, text, gmask, H4);

  // MLP: dp1 split -> (dp2 split with inline dp1-reduce+GELU) -> final reduce
  dp_split<<<dim3(DHN / 64, 32), blk, 0, stream>>>(H4, dp1W, P1, DD, DHN);
  dp_split2g<<<dim3(DINN / 64, 32), blk, 0, stream>>>(P1, dp1b, dp2W, P2, DHN, DINN);
  dp_reduce<0><<<dim3(DINN / 256, NB), blk, 0, stream>>>(P2, dp2b, Z, DINN);
}

// Round 13
// 160.751 us; speedup vs baseline: 1.6099x; 1.6099x over previous
//
#include <hip/hip_runtime.h>
#include <hip/hip_bf16.h>
#include <math.h>

#define NB 8        // batch
#define LNN 64      // nodes
#define LTN 256     // text len
#define DD 1024     // model dim
#define NH 4        // heads (each full width D)
#define HDD 4096    // NH*DD
#define DINN 2048
#define DHN 1024    // DIN/2

// 2*log2(e): tanh(x) = 1 - 2/(exp2(x*C)+1)
#define C_TANH 2.8853900817779268f

typedef __bf16 bf16x8 __attribute__((ext_vector_type(8)));
typedef float f32x4 __attribute__((ext_vector_type(4)));

__device__ __forceinline__ ushort f2b(float f) {
  unsigned int u = __builtin_bit_cast(unsigned int, f);
  u = (u + 0x7FFFu + ((u >> 16) & 1u)) >> 16;
  return (ushort)u;
}

// ---------------- mega-prep: activations cvt + all 6 weight transposes, 1 launch ----------------
__global__ __launch_bounds__(256) void prep(const float* __restrict__ node,
                                            ushort* __restrict__ node_bf,
                                            const float* __restrict__ text,
                                            ushort* __restrict__ text_bf,
                                            const float* __restrict__ Wq,
                                            const float* __restrict__ Wk,
                                            const float* __restrict__ Wv,
                                            const float* __restrict__ Wo,
                                            const float* __restrict__ aqW,
                                            const float* __restrict__ akW,
                                            ushort* __restrict__ TwtQKV,
                                            ushort* __restrict__ TwtWo,
                                            ushort* __restrict__ TwtAQ) {
  int bid = blockIdx.x;
  int t = threadIdx.x;
  if (bid < 1280) {
    const float* in;
    ushort* out;
    int i;
    if (bid < 256) { in = node; out = node_bf; i = (bid * 256 + t) * 8; }
    else { in = text; out = text_bf; i = ((bid - 256) * 256 + t) * 8; }
    float4 a = *(const float4*)(in + i);
    float4 b = *(const float4*)(in + i + 4);
    ushort4 o0 = {f2b(a.x), f2b(a.y), f2b(a.z), f2b(a.w)};
    ushort4 o1 = {f2b(b.x), f2b(b.y), f2b(b.z), f2b(b.w)};
    *(ushort4*)(out + i) = o0;
    *(ushort4*)(out + i + 4) = o1;
    return;
  }
  bid -= 1280;
  const float* W;
  ushort* dst0;
  int K, N, tt;
  if (bid < 3072) {
    int z = bid >> 10;
    tt = bid & 1023;
    W = (z == 0) ? Wq : ((z == 1) ? Wk : Wv);
    dst0 = TwtQKV + (size_t)z * DD * HDD;
    K = DD; N = HDD;
  } else if (bid < 4096) {
    tt = bid - 3072; W = Wo; dst0 = TwtWo; K = HDD; N = DD;
  } else if (bid < 4352) {
    tt = bid - 4096; W = aqW; dst0 = TwtAQ; K = DD; N = DD;
  } else {
    tt = bid - 4352; W = akW; dst0 = TwtAQ + (size_t)DD * DD; K = DD; N = DD;
  }
  int ntn = N >> 6;
  int n0 = (tt % ntn) << 6, k0 = (tt / ntn) << 6;
  __shared__ float tf[64][65];
  int r = t >> 2, c4 = (t & 3) * 16;
  const float* src = W + (size_t)(k0 + r) * N + n0 + c4;
  float4 v0 = *(const float4*)(src);
  float4 v1 = *(const float4*)(src + 4);
  float4 v2 = *(const float4*)(src + 8);
  float4 v3 = *(const float4*)(src + 12);
  *(float4*)&tf[r][c4] = v0;
  *(float4*)&tf[r][c4 + 4] = v1;
  *(float4*)&tf[r][c4 + 8] = v2;
  *(float4*)&tf[r][c4 + 12] = v3;
  __syncthreads();
  int nl = t >> 2, kc = (t & 3) * 16;
  ushort tmp[16];
#pragma unroll
  for (int j = 0; j < 16; ++j) tmp[j] = f2b(tf[kc + j][nl]);
  ushort* dst = dst0 + (size_t)(n0 + nl) * K + k0 + kc;
  *(uint4*)(dst) = *(uint4*)&tmp[0];
  *(uint4*)(dst + 8) = *(uint4*)&tmp[8];
}

// ---------------- QKV gemm (3 via grid.z): 64x128 tile, bf16 out, +bias ----------------
__global__ __launch_bounds__(256) void gemm_qkv3(const ushort* __restrict__ A,
                                                 const ushort* __restrict__ BtB,
                                                 const float* __restrict__ b0,
                                                 const float* __restrict__ b1,
                                                 const float* __restrict__ b2,
                                                 ushort* __restrict__ o0,
                                                 ushort* __restrict__ o1,
                                                 ushort* __restrict__ o2,
                                                 int M, int N, int K) {
  int z = blockIdx.z;
  const ushort* Bt = BtB + (size_t)z * N * K;
  const float* bias = (z == 0) ? b0 : ((z == 1) ? b1 : b2);
  ushort* Cout = (z == 0) ? o0 : ((z == 1) ? o1 : o2);
  __shared__ ushort Als[64 * 64];
  __shared__ ushort Bls[128 * 64];
  int tid = threadIdx.x;
  int m0 = blockIdx.y << 6, n0 = blockIdx.x << 7;
  int srow = tid >> 3, su = tid & 7;
  int sx = (su ^ (srow & 7)) * 8;
  const ushort* ga = A + (size_t)(m0 + srow) * K + su * 8;
  const ushort* gb = Bt + (size_t)(n0 + srow) * K + su * 8;
  int wa0 = srow * 64 + sx, wa1 = (srow + 32) * 64 + sx;
  int wb2 = (srow + 64) * 64 + sx, wb3 = (srow + 96) * 64 + sx;
  const size_t rs32 = (size_t)32 * K;
  int lane = tid & 63, w = tid >> 6;
  int wm = w >> 1, wn = w & 1;
  int r = lane & 15, kg = lane >> 4;
  f32x4 acc[2][4] = {};
  uint4 pa0 = *(const uint4*)(ga);
  uint4 pa1 = *(const uint4*)(ga + rs32);
  uint4 pb0 = *(const uint4*)(gb);
  uint4 pb1 = *(const uint4*)(gb + rs32);
  uint4 pb2 = *(const uint4*)(gb + 2 * rs32);
  uint4 pb3 = *(const uint4*)(gb + 3 * rs32);
  for (int k0 = 0; k0 < K; k0 += 64) {
    __syncthreads();
    *(uint4*)&Als[wa0] = pa0; *(uint4*)&Als[wa1] = pa1;
    *(uint4*)&Bls[wa0] = pb0; *(uint4*)&Bls[wa1] = pb1;
    *(uint4*)&Bls[wb2] = pb2; *(uint4*)&Bls[wb3] = pb3;
    __syncthreads();
    int kn = k0 + 64;
    if (kn < K) {
      pa0 = *(const uint4*)(ga + kn);
      pa1 = *(const uint4*)(ga + rs32 + kn);
      pb0 = *(const uint4*)(gb + kn);
      pb1 = *(const uint4*)(gb + rs32 + kn);
      pb2 = *(const uint4*)(gb + 2 * rs32 + kn);
      pb3 = *(const uint4*)(gb + 3 * rs32 + kn);
    }
#pragma unroll
    for (int h = 0; h < 2; ++h) {
      int sa = ((h * 4 + kg) ^ (r & 7)) * 8;
      bf16x8 af[2], bfr[4];
#pragma unroll
      for (int m = 0; m < 2; ++m)
        af[m] = *(const bf16x8*)&Als[(wm * 32 + m * 16 + r) * 64 + sa];
#pragma unroll
      for (int n = 0; n < 4; ++n)
        bfr[n] = *(const bf16x8*)&Bls[(wn * 64 + n * 16 + r) * 64 + sa];
#pragma unroll
      for (int m = 0; m < 2; ++m)
#pragma unroll
        for (int n = 0; n < 4; ++n)
          acc[m][n] = __builtin_amdgcn_mfma_f32_16x16x32_bf16(af[m], bfr[n], acc[m][n], 0, 0, 0);
    }
  }
#pragma unroll
  for (int m = 0; m < 2; ++m)
#pragma unroll
    for (int n = 0; n < 4; ++n) {
      f32x4 a = acc[m][n];
#pragma unroll
      for (int v = 0; v < 4; ++v) {
        int row = m0 + wm * 32 + m * 16 + kg * 4 + v;
        int col = n0 + wn * 64 + n * 16 + r;
        Cout[(size_t)row * N + col] = f2b(a[v] + bias[col]);
      }
    }
}

// ---------------- Wo gemm with split-K 4 (grid.z): fp32 partials ----------------
__global__ __launch_bounds__(256) void gemm_wo_split(const ushort* __restrict__ A,
                                                     const ushort* __restrict__ Bt,
                                                     float* __restrict__ P,
                                                     int M, int N, int K) {
  __shared__ ushort Als[64 * 64];
  __shared__ ushort Bls[128 * 64];
  int tid = threadIdx.x;
  int m0 = blockIdx.y << 6, n0 = blockIdx.x << 7;
  int Ks = K >> 2, kbase = blockIdx.z * Ks;
  int srow = tid >> 3, su = tid & 7;
  int sx = (su ^ (srow & 7)) * 8;
  const ushort* ga = A + (size_t)(m0 + srow) * K + kbase + su * 8;
  const ushort* gb = Bt + (size_t)(n0 + srow) * K + kbase + su * 8;
  int wa0 = srow * 64 + sx, wa1 = (srow + 32) * 64 + sx;
  int wb2 = (srow + 64) * 64 + sx, wb3 = (srow + 96) * 64 + sx;
  const size_t rs32 = (size_t)32 * K;
  int lane = tid & 63, w = tid >> 6;
  int wm = w >> 1, wn = w & 1;
  int r = lane & 15, kg = lane >> 4;
  f32x4 acc[2][4] = {};
  uint4 pa0 = *(const uint4*)(ga);
  uint4 pa1 = *(const uint4*)(ga + rs32);
  uint4 pb0 = *(const uint4*)(gb);
  uint4 pb1 = *(const uint4*)(gb + rs32);
  uint4 pb2 = *(const uint4*)(gb + 2 * rs32);
  uint4 pb3 = *(const uint4*)(gb + 3 * rs32);
  for (int k0 = 0; k0 < Ks; k0 += 64) {
    __syncthreads();
    *(uint4*)&Als[wa0] = pa0; *(uint4*)&Als[wa1] = pa1;
    *(uint4*)&Bls[wa0] = pb0; *(uint4*)&Bls[wa1] = pb1;
    *(uint4*)&Bls[wb2] = pb2; *(uint4*)&Bls[wb3] = pb3;
    __syncthreads();
    int kn = k0 + 64;
    if (kn < Ks) {
      pa0 = *(const uint4*)(ga + kn);
      pa1 = *(const uint4*)(ga + rs32 + kn);
      pb0 = *(const uint4*)(gb + kn);
      pb1 = *(const uint4*)(gb + rs32 + kn);
      pb2 = *(const uint4*)(gb + 2 * rs32 + kn);
      pb3 = *(const uint4*)(gb + 3 * rs32 + kn);
    }
#pragma unroll
    for (int h = 0; h < 2; ++h) {
      int sa = ((h * 4 + kg) ^ (r & 7)) * 8;
      bf16x8 af[2], bfr[4];
#pragma unroll
      for (int m = 0; m < 2; ++m)
        af[m] = *(const bf16x8*)&Als[(wm * 32 + m * 16 + r) * 64 + sa];
#pragma unroll
      for (int n = 0; n < 4; ++n)
        bfr[n] = *(const bf16x8*)&Bls[(wn * 64 + n * 16 + r) * 64 + sa];
#pragma unroll
      for (int m = 0; m < 2; ++m)
#pragma unroll
        for (int n = 0; n < 4; ++n)
          acc[m][n] = __builtin_amdgcn_mfma_f32_16x16x32_bf16(af[m], bfr[n], acc[m][n], 0, 0, 0);
    }
  }
#pragma unroll
  for (int m = 0; m < 2; ++m)
#pragma unroll
    for (int n = 0; n < 4; ++n) {
      f32x4 a = acc[m][n];
#pragma unroll
      for (int v = 0; v < 4; ++v) {
        int row = m0 + wm * 32 + m * 16 + kg * 4 + v;
        int col = n0 + wn * 64 + n * 16 + r;
        P[((size_t)blockIdx.z * M + row) * N + col] = a[v];
      }
    }
}

// ---------------- aq+ak gemm (M-concat row select): fp32 out, *C_TANH ----------------
__global__ __launch_bounds__(256) void gemm_aqak(const ushort* __restrict__ H2,
                                                 const ushort* __restrict__ Tbf,
                                                 const ushort* __restrict__ TwtAQ,
                                                 const float* __restrict__ aqb,
                                                 const float* __restrict__ akb,
                                                 const float* __restrict__ attb,
                                                 float* __restrict__ QBu,
                                                 float* __restrict__ KAB,
                                                 int N, int K) {
  __shared__ ushort Als[64 * 64];
  __shared__ ushort Bls[128 * 64];
  int tid = threadIdx.x;
  int gm0 = blockIdx.y << 6, n0 = blockIdx.x << 7;
  const ushort* Abase;
  const ushort* Bt;
  const float* bias;
  const float* bias2;
  float* Obase;
  if (gm0 < 512) {
    Abase = H2 + (size_t)gm0 * K;
    Bt = TwtAQ;
    bias = aqb; bias2 = nullptr;
    Obase = QBu + (size_t)gm0 * N;
  } else {
    Abase = Tbf + (size_t)(gm0 - 512) * K;
    Bt = TwtAQ + (size_t)N * K;
    bias = akb; bias2 = attb;
    Obase = KAB + (size_t)(gm0 - 512) * N;
  }
  int srow = tid >> 3, su = tid & 7;
  int sx = (su ^ (srow & 7)) * 8;
  const ushort* ga = Abase + (size_t)srow * K + su * 8;
  const ushort* gb = Bt + (size_t)(n0 + srow) * K + su * 8;
  int wa0 = srow * 64 + sx, wa1 = (srow + 32) * 64 + sx;
  int wb2 = (srow + 64) * 64 + sx, wb3 = (srow + 96) * 64 + sx;
  const size_t rs32 = (size_t)32 * K;
  int lane = tid & 63, w = tid >> 6;
  int wm = w >> 1, wn = w & 1;
  int r = lane & 15, kg = lane >> 4;
  f32x4 acc[2][4] = {};
  uint4 pa0 = *(const uint4*)(ga);
  uint4 pa1 = *(const uint4*)(ga + rs32);
  uint4 pb0 = *(const uint4*)(gb);
  uint4 pb1 = *(const uint4*)(gb + rs32);
  uint4 pb2 = *(const uint4*)(gb + 2 * rs32);
  uint4 pb3 = *(const uint4*)(gb + 3 * rs32);
  for (int k0 = 0; k0 < K; k0 += 64) {
    __syncthreads();
    *(uint4*)&Als[wa0] = pa0; *(uint4*)&Als[wa1] = pa1;
    *(uint4*)&Bls[wa0] = pb0; *(uint4*)&Bls[wa1] = pb1;
    *(uint4*)&Bls[wb2] = pb2; *(uint4*)&Bls[wb3] = pb3;
    __syncthreads();
    int kn = k0 + 64;
    if (kn < K) {
      pa0 = *(const uint4*)(ga + kn);
      pa1 = *(const uint4*)(ga + rs32 + kn);
      pb0 = *(const uint4*)(gb + kn);
      pb1 = *(const uint4*)(gb + rs32 + kn);
      pb2 = *(const uint4*)(gb + 2 * rs32 + kn);
      pb3 = *(const uint4*)(gb + 3 * rs32 + kn);
    }
#pragma unroll
    for (int h = 0; h < 2; ++h) {
      int sa = ((h * 4 + kg) ^ (r & 7)) * 8;
      bf16x8 af[2], bfr[4];
#pragma unroll
      for (int m = 0; m < 2; ++m)
        af[m] = *(const bf16x8*)&Als[(wm * 32 + m * 16 + r) * 64 + sa];
#pragma unroll
      for (int n = 0; n < 4; ++n)
        bfr[n] = *(const bf16x8*)&Bls[(wn * 64 + n * 16 + r) * 64 + sa];
#pragma unroll
      for (int m = 0; m < 2; ++m)
#pragma unroll
        for (int n = 0; n < 4; ++n)
          acc[m][n] = __builtin_amdgcn_mfma_f32_16x16x32_bf16(af[m], bfr[n], acc[m][n], 0, 0, 0);
    }
  }
#pragma unroll
  for (int m = 0; m < 2; ++m)
#pragma unroll
    for (int n = 0; n < 4; ++n) {
      f32x4 a = acc[m][n];
#pragma unroll
      for (int v = 0; v < 4; ++v) {
        int lrow = wm * 32 + m * 16 + kg * 4 + v;
        int col = n0 + wn * 64 + n * 16 + r;
        float x = a[v] + bias[col];
        if (bias2) x += bias2[col];
        Obase[(size_t)lrow * N + col] = x * C_TANH;
      }
    }
}

// ---------------- Wo split-K(4) reduce + bias + residual + LayerNorm -> bf16 ----------------
__global__ __launch_bounds__(256) void wo_ln(const float* __restrict__ P,
                                             const float* __restrict__ bo,
                                             const float* __restrict__ node,
                                             const float* __restrict__ g,
                                             const float* __restrict__ be,
                                             ushort* __restrict__ Y) {
  int row = blockIdx.x, tid = threadIdx.x;
  int c = tid * 4;
  const size_t MN = (size_t)512 * 1024;
  size_t o = (size_t)row * DD + c;
  float4 v0 = *(const float4*)(P + o);
  float4 v1 = *(const float4*)(P + MN + o);
  float4 v2 = *(const float4*)(P + 2 * MN + o);
  float4 v3 = *(const float4*)(P + 3 * MN + o);
  float4 rv = *(const float4*)(node + o);
  float4 bv = *(const float4*)(bo + c);
  float4 v;
  v.x = v0.x + v1.x + v2.x + v3.x + rv.x + bv.x;
  v.y = v0.y + v1.y + v2.y + v3.y + rv.y + bv.y;
  v.z = v0.z + v1.z + v2.z + v3.z + rv.z + bv.z;
  v.w = v0.w + v1.w + v2.w + v3.w + rv.w + bv.w;
  float s = v.x + v.y + v.z + v.w;
  float ss = v.x * v.x + v.y * v.y + v.z * v.z + v.w * v.w;
  for (int o2 = 32; o2; o2 >>= 1) {
    s += __shfl_xor(s, o2, 64);
    ss += __shfl_xor(ss, o2, 64);
  }
  __shared__ float rb_[8];
  int lane = tid & 63, w = tid >> 6;
  if (lane == 0) { rb_[w] = s; rb_[4 + w] = ss; }
  __syncthreads();
  s = rb_[0] + rb_[1] + rb_[2] + rb_[3];
  ss = rb_[4] + rb_[5] + rb_[6] + rb_[7];
  float mu = s * (1.f / 1024.f);
  float var = ss * (1.f / 1024.f) - mu * mu;
  float rstd = rsqrtf(var + 1e-5f);
  ushort4 o4;
  o4.x = f2b((v.x - mu) * rstd * g[c + 0] + be[c + 0]);
  o4.y = f2b((v.y - mu) * rstd * g[c + 1] + be[c + 1]);
  o4.z = f2b((v.z - mu) * rstd * g[c + 2] + be[c + 2]);
  o4.w = f2b((v.w - mu) * rstd * g[c + 3] + be[c + 3]);
  *(ushort4*)(Y + (size_t)row * DD + c) = o4;
}

// ---------------- fused attention: per (bh, dtile) full QK^T + softmax + PV ----------------
__global__ __launch_bounds__(256) void attn_one(const ushort* __restrict__ Qb,
                                                const ushort* __restrict__ Kb,
                                                const ushort* __restrict__ Vb,
                                                const int* __restrict__ gmask,
                                                ushort* __restrict__ AO) {
  int bid = blockIdx.x;
  int bh = bid >> 3, dt = bid & 7;
  int b = bh >> 2;
  int d0 = dt * 128;
  size_t base = ((size_t)b * LNN) * HDD + (size_t)(bh & 3) * DD;
  __shared__ ushort Als[64 * 64];
  __shared__ ushort Bls[64 * 64];
  __shared__ float S[64][68];
  __shared__ ushort Pls[64 * 72];
  __shared__ ushort Vt[128 * 72];
  int tid = threadIdx.x;
  int lane = tid & 63, w = tid >> 6;
  int wm = w >> 1, wn = w & 1;
  int r = lane & 15, kg = lane >> 4;
  {
    int srow = tid >> 2, su0 = (tid & 3) * 2;
    const ushort* ga = Qb + base + (size_t)srow * HDD + su0 * 8;
    const ushort* gb = Kb + base + (size_t)srow * HDD + su0 * 8;
    int wa0 = srow * 64 + ((su0) ^ (srow & 7)) * 8;
    int wa1 = srow * 64 + ((su0 + 1) ^ (srow & 7)) * 8;
    f32x4 acc[2][2] = {};
    uint4 pa0 = *(const uint4*)(ga);
    uint4 pa1 = *(const uint4*)(ga + 8);
    uint4 pb0 = *(const uint4*)(gb);
    uint4 pb1 = *(const uint4*)(gb + 8);
    for (int k0 = 0; k0 < DD; k0 += 64) {
      __syncthreads();
      *(uint4*)&Als[wa0] = pa0; *(uint4*)&Als[wa1] = pa1;
      *(uint4*)&Bls[wa0] = pb0; *(uint4*)&Bls[wa1] = pb1;
      __syncthreads();
      int kn = k0 + 64;
      if (kn < DD) {
        pa0 = *(const uint4*)(ga + kn);
        pa1 = *(const uint4*)(ga + kn + 8);
        pb0 = *(const uint4*)(gb + kn);
        pb1 = *(const uint4*)(gb + kn + 8);
      }
#pragma unroll
      for (int h = 0; h < 2; ++h) {
        int sa = ((h * 4 + kg) ^ (r & 7)) * 8;
        bf16x8 af[2], bfr[2];
#pragma unroll
        for (int m = 0; m < 2; ++m)
          af[m] = *(const bf16x8*)&Als[(wm * 32 + m * 16 + r) * 64 + sa];
#pragma unroll
        for (int n = 0; n < 2; ++n)
          bfr[n] = *(const bf16x8*)&Bls[(wn * 32 + n * 16 + r) * 64 + sa];
#pragma unroll
        for (int m = 0; m < 2; ++m)
#pragma unroll
          for (int n = 0; n < 2; ++n)
            acc[m][n] = __builtin_amdgcn_mfma_f32_16x16x32_bf16(af[m], bfr[n], acc[m][n], 0, 0, 0);
      }
    }
#pragma unroll
    for (int m = 0; m < 2; ++m)
#pragma unroll
      for (int n = 0; n < 2; ++n)
#pragma unroll
        for (int v = 0; v < 4; ++v)
          S[wm * 32 + m * 16 + kg * 4 + v][wn * 32 + n * 16 + r] = acc[m][n][v];
  }
  {
    int kq = lane, dq = w * 32;
    const ushort* src = Vb + base + (size_t)kq * HDD + d0 + dq;
    uint4 v0 = *(const uint4*)src;
    uint4 v1 = *(const uint4*)(src + 8);
    uint4 v2 = *(const uint4*)(src + 16);
    uint4 v3 = *(const uint4*)(src + 24);
    ushort tmp[32];
    *(uint4*)&tmp[0] = v0; *(uint4*)&tmp[8] = v1;
    *(uint4*)&tmp[16] = v2; *(uint4*)&tmp[24] = v3;
#pragma unroll
    for (int j = 0; j < 32; ++j) Vt[(dq + j) * 72 + kq] = tmp[j];
  }
  __syncthreads();
  bool valid = gmask[b * LNN + lane] != 0;
  for (int i = 0; i < 16; ++i) {
    int q = w * 16 + i;
    float v = valid ? S[q][lane] * 0.03125f : -__builtin_inff();
    float mx = v;
    for (int o = 32; o; o >>= 1) mx = fmaxf(mx, __shfl_xor(mx, o, 64));
    float e = valid ? __expf(v - mx) : 0.f;
    float s = e;
    for (int o = 32; o; o >>= 1) s += __shfl_xor(s, o, 64);
    Pls[q * 72 + lane] = f2b(__fdividef(e, s));
  }
  __syncthreads();
  f32x4 acc[2][4] = {};
#pragma unroll
  for (int h = 0; h < 2; ++h) {
    int ko = h * 32 + kg * 8;
    bf16x8 af[2], bfr[4];
#pragma unroll
    for (int m = 0; m < 2; ++m)
      af[m] = *(const bf16x8*)&Pls[(wm * 32 + m * 16 + r) * 72 + ko];
#pragma unroll
    for (int n = 0; n < 4; ++n)
      bfr[n] = *(const bf16x8*)&Vt[(wn * 64 + n * 16 + r) * 72 + ko];
#pragma unroll
    for (int m = 0; m < 2; ++m)
#pragma unroll
      for (int n = 0; n < 4; ++n)
        acc[m][n] = __builtin_amdgcn_mfma_f32_16x16x32_bf16(af[m], bfr[n], acc[m][n], 0, 0, 0);
  }
#pragma unroll
  for (int m = 0; m < 2; ++m)
#pragma unroll
    for (int n = 0; n < 4; ++n) {
      f32x4 a = acc[m][n];
#pragma unroll
      for (int v = 0; v < 4; ++v) {
        int q = wm * 32 + m * 16 + kg * 4 + v;
        int col = wn * 64 + n * 16 + r;
        AO[base + (size_t)q * HDD + d0 + col] = f2b(a[v]);
      }
    }
}

// ---------------- additive attention phase 1: 8-q reuse, 128-d slices ----------------
__global__ __launch_bounds__(256) void addatt_e(const float* __restrict__ QBu,
                                                const float* __restrict__ KAB,
                                                const float* __restrict__ av_,
                                                float* __restrict__ E8) {
  int ds = blockIdx.x, qt = blockIdx.y, b = blockIdx.z;
  int tid = threadIdx.x;
  __shared__ float qs[8][128];
  __shared__ float avs[128];
  __shared__ float red[4];
  int bq0 = b * LNN + qt * 8;
  {
    int qq = tid >> 5, dd = (tid & 31) * 4;
    *(float4*)&qs[qq][dd] = *(const float4*)(QBu + (size_t)(bq0 + qq) * DD + ds * 128 + dd);
  }
  float av = (tid < 128) ? av_[ds * 128 + tid] : 0.f;
  if (tid < 128) avs[tid] = av;
  float s = av;
  for (int o = 32; o; o >>= 1) s += __shfl_xor(s, o, 64);
  int lane = tid & 63, w = tid >> 6;
  if (lane == 0) red[w] = s;
  __syncthreads();
  float sumav = red[0] + red[1] + red[2] + red[3];
  const float* kr = KAB + (size_t)(b * LTN + tid) * DD + ds * 128;
  float ac[8] = {};
#pragma unroll 2
  for (int d = 0; d < 128; d += 4) {
    float4 kv = *(const float4*)(kr + d);
    float4 av4 = *(const float4*)&avs[d];
#pragma unroll
    for (int qq = 0; qq < 8; ++qq) {
      float4 q4 = *(const float4*)&qs[qq][d];
      ac[qq] = fmaf(av4.x, __builtin_amdgcn_rcpf(__builtin_amdgcn_exp2f(q4.x + kv.x) + 1.f), ac[qq]);
      ac[qq] = fmaf(av4.y, __builtin_amdgcn_rcpf(__builtin_amdgcn_exp2f(q4.y + kv.y) + 1.f), ac[qq]);
      ac[qq] = fmaf(av4.z, __builtin_amdgcn_rcpf(__builtin_amdgcn_exp2f(q4.z + kv.z) + 1.f), ac[qq]);
      ac[qq] = fmaf(av4.w, __builtin_amdgcn_rcpf(__builtin_amdgcn_exp2f(q4.w + kv.w) + 1.f), ac[qq]);
    }
  }
  size_t ebase = ((size_t)ds * 512 + bq0) * LTN + tid;
#pragma unroll
  for (int qq = 0; qq < 8; ++qq)
    E8[ebase + (size_t)qq * LTN] = sumav - 2.f * ac[qq];
}

// ---------------- additive attention phase 2: sum 8 partials + masked softmax ----------------
__global__ __launch_bounds__(256) void addatt_sm(const float* __restrict__ E8,
                                                 const int* __restrict__ lmask,
                                                 float* __restrict__ Wv) {
  int bq = blockIdx.x;
  int b = bq >> 6;
  int tid = threadIdx.x;
  __shared__ float rb_[8];
  float e = 0.f;
#pragma unroll
  for (int ks = 0; ks < 8; ++ks)
    e += E8[((size_t)ks * 512 + bq) * LTN + tid];
  bool valid = lmask[b * LTN + tid] != 0;
  float v = valid ? e : -__builtin_inff();
  int lane = tid & 63, w = tid >> 6;
  float m = v;
  for (int o = 32; o; o >>= 1) m = fmaxf(m, __shfl_xor(m, o, 64));
  if (lane == 0) rb_[w] = m;
  __syncthreads();
  m = fmaxf(fmaxf(rb_[0], rb_[1]), fmaxf(rb_[2], rb_[3]));
  float ex = valid ? __expf(v - m) : 0.f;
  float sm = ex;
  for (int o = 32; o; o >>= 1) sm += __shfl_xor(sm, o, 64);
  if (lane == 0) rb_[4 + w] = sm;
  __syncthreads();
  sm = rb_[4] + rb_[5] + rb_[6] + rb_[7];
  Wv[(size_t)bq * LTN + tid] = __fdividef(ex, sm);
}

// ---------------- additive attention phase 3: pooled context ----------------
__global__ __launch_bounds__(256) void addatt_pool(const float* __restrict__ Wv,
                                                   const float* __restrict__ text,
                                                   const int* __restrict__ gmask,
                                                   float* __restrict__ H4) {
  int dt = blockIdx.x, b = blockIdx.y;
  int tid = threadIdx.x;
  __shared__ float cf[LTN];
  float c = 0.f, cnt = 0.f;
#pragma unroll 8
  for (int q = 0; q < LNN; ++q) {
    float m = (gmask[b * LNN + q] != 0) ? 1.f : 0.f;
    cnt += m;
    c = fmaf(m, Wv[(size_t)(b * LNN + q) * LTN + tid], c);
  }
  cf[tid] = c;
  cnt = fmaxf(cnt, 9.765625e-04f);
  __syncthreads();
  int d = dt * 256 + tid;
  const float* tb = text + (size_t)b * LTN * DD + d;
  float acc = 0.f;
#pragma unroll 8
  for (int k = 0; k < LTN; ++k) acc = fmaf(cf[k], tb[(size_t)k * DD], acc);
  H4[b * DD + d] = acc / cnt;
}

// ---------------- split-K GEMV (dp1) ----------------
__global__ __launch_bounds__(256) void dp_split(const float* __restrict__ X,
                                                const float* __restrict__ W,
                                                float* __restrict__ P,
                                                int K, int N) {
  int jt = blockIdx.x, kt = blockIdx.y;
  int t = threadIdx.x;
  __shared__ float xs[8][32];
  if (t < 64) {
    int b = t >> 3, kk = (t & 7) * 4;
    *(float4*)&xs[b][kk] = *(const float4*)(X + (size_t)b * K + kt * 32 + kk);
  }
  __syncthreads();
  int j = jt * 64 + (t & 63);
  int bg = (t >> 6) * 2;
  const float* wp = W + (size_t)(kt * 32) * N + j;
  float a0 = 0.f, a1 = 0.f;
#pragma unroll
  for (int k = 0; k < 32; ++k) {
    float w = wp[(size_t)k * N];
    a0 = fmaf(xs[bg + 0][k], w, a0);
    a1 = fmaf(xs[bg + 1][k], w, a1);
  }
  P[((size_t)kt * 8 + bg + 0) * N + j] = a0;
  P[((size_t)kt * 8 + bg + 1) * N + j] = a1;
}

// ---------------- dp2 split-K GEMV with inline dp1-reduce + GELU ----------------
__global__ __launch_bounds__(256) void dp_split2g(const float* __restrict__ P1,
                                                  const float* __restrict__ b1,
                                                  const float* __restrict__ W,
                                                  float* __restrict__ P,
                                                  int K, int N) {
  int jt = blockIdx.x, kt = blockIdx.y;
  int t = threadIdx.x;
  __shared__ float xs[8][32];
  {
    int b = t >> 5, kk = t & 31;
    int j = kt * 32 + kk;
    float s = b1[j];
#pragma unroll 8
    for (int p = 0; p < 32; ++p) s += P1[((size_t)p * 8 + b) * K + j];
    xs[b][kk] = 0.5f * s * (1.f + erff(s * 0.70710678118654752440f));
  }
  __syncthreads();
  int j = jt * 64 + (t & 63);
  int bg = (t >> 6) * 2;
  const float* wp = W + (size_t)(kt * 32) * N + j;
  float a0 = 0.f, a1 = 0.f;
#pragma unroll
  for (int k = 0; k < 32; ++k) {
    float w = wp[(size_t)k * N];
    a0 = fmaf(xs[bg + 0][k], w, a0);
    a1 = fmaf(xs[bg + 1][k], w, a1);
  }
  P[((size_t)kt * 8 + bg + 0) * N + j] = a0;
  P[((size_t)kt * 8 + bg + 1) * N + j] = a1;
}

template <int GELU>
__global__ __launch_bounds__(256) void dp_reduce(const float* __restrict__ P,
                                                 const float* __restrict__ bias,
                                                 float* __restrict__ O, int N) {
  int b = blockIdx.y;
  int j = blockIdx.x * 256 + threadIdx.x;
  float s = bias[j];
#pragma unroll 8
  for (int kt = 0; kt < 32; ++kt) s += P[((size_t)kt * 8 + b) * N + j];
  if constexpr (GELU) s = 0.5f * s * (1.f + erff(s * 0.70710678118654752440f));
  O[(size_t)b * N + j] = s;
}

extern "C" void kernel_launch(void* const* d_in, const int* in_sizes, int n_in,
                              void* d_out, int out_size, void* d_ws, size_t ws_size,
                              hipStream_t stream) {
  const float* text = (const float*)d_in[0];
  const float* node = (const float*)d_in[1];
  const float* Wq = (const float*)d_in[2];
  const float* bq = (const float*)d_in[3];
  const float* Wk = (const float*)d_in[4];
  const float* bk = (const float*)d_in[5];
  const float* Wv = (const float*)d_in[6];
  const float* bv = (const float*)d_in[7];
  const float* Wo = (const float*)d_in[8];
  const float* bo = (const float*)d_in[9];
  const float* lng = (const float*)d_in[10];
  const float* lnb = (const float*)d_in[11];
  const float* aqW = (const float*)d_in[12];
  const float* aqb = (const float*)d_in[13];
  const float* akW = (const float*)d_in[14];
  const float* akb = (const float*)d_in[15];
  const float* attv = (const float*)d_in[16];
  const float* attb = (const float*)d_in[17];
  const float* dp1W = (const float*)d_in[18];
  const float* dp1b = (const float*)d_in[19];
  const float* dp2W = (const float*)d_in[20];
  const float* dp2b = (const float*)d_in[21];
  const int* gmask = (const int*)d_in[22];
  const int* lmask = (const int*)d_in[23];
  (void)in_sizes; (void)n_in; (void)out_size; (void)ws_size;

  char* base = (char*)d_ws;
#define MB(x) (((size_t)(x)) << 20)
  ushort* TwtQKV = (ushort*)(base);                 // 0..24 MB
  ushort* TwtWo = (ushort*)(base + MB(24));         // 24..32
  ushort* TwtAQ = (ushort*)(base + MB(32));         // 32..36
  ushort* node_bf = (ushort*)(base + MB(36));       // 36..37
  ushort* text_bf = (ushort*)(base + MB(37));       // 37..41
  ushort* Qb = (ushort*)(base + MB(41));            // 41..45
  ushort* Kb = (ushort*)(base + MB(45));            // 45..49
  ushort* Vb = (ushort*)(base + MB(49));            // 49..53
  ushort* AO = (ushort*)(base + MB(53));            // 53..57
  float* P_Wo = (float*)(base + MB(61));            // 61..69 (4 slices x 2MB)
  ushort* H2 = (ushort*)(base + MB(69));            // 69..70
  float* QBu = (float*)(base + MB(70));             // 70..72
  float* KAB = (float*)(base + MB(72));             // 72..80
  float* E8 = (float*)(base + MB(80));              // 80..84
  float* Wvb = (float*)(base + MB(84));             // 84..84.5
  float* H4 = (float*)(base + MB(84) + (512 << 10));   // 32KB
  float* P1 = (float*)(base + MB(85));              // 85..86
  float* P2 = (float*)(base + MB(86));              // 86..88
  float* Z = (float*)d_out;
#undef MB

  const int M1 = NB * LNN;  // 512
  dim3 blk(256);

  // one launch: activations cvt + all 6 weight transposes
  prep<<<dim3(5888), blk, 0, stream>>>(node, node_bf, text, text_bf,
                                       Wq, Wk, Wv, Wo, aqW, akW,
                                       TwtQKV, TwtWo, TwtAQ);

  // QKV projections (64x128 tiles, grid.z = 3)
  gemm_qkv3<<<dim3(HDD / 128, M1 / 64, 3), blk, 0, stream>>>(node_bf, TwtQKV, bq, bk, bv, Qb, Kb, Vb, M1, HDD, DD);

  // fused self-attention: QK^T (redundant per d-tile) + softmax + PV, 256 blocks
  attn_one<<<dim3(NB * NH * 8), blk, 0, stream>>>(Qb, Kb, Vb, gmask, AO);

  // output proj: split-K 4-way partials, then fused reduce+residual+LayerNorm
  gemm_wo_split<<<dim3(DD / 128, M1 / 64, 4), blk, 0, stream>>>(AO, TwtWo, P_Wo, M1, DD, HDD);
  wo_ln<<<dim3(M1), blk, 0, stream>>>(P_Wo, bo, node, lng, lnb, H2);

  // aq + ak (M-concat), outputs pre-scaled by C_TANH
  gemm_aqak<<<dim3(DD / 128, 40), blk, 0, stream>>>(H2, text_bf, TwtAQ, aqb, akb, attb, QBu, KAB, DD, DD);

  // additive attention: partial-e (8-q reuse, 8 d-slices) -> softmax -> pooled context
  addatt_e<<<dim3(8, 8, NB), blk, 0, stream>>>(QBu, KAB, attv, E8);
  addatt_sm<<<dim3(M1), blk, 0, stream>>>(E8, lmask, Wvb);
  addatt_pool<<<dim3(4, NB), blk, 0, stream>>>(Wvb, text, gmask, H4);

  // MLP: dp1 split -> (dp2 split with inline dp1-reduce+GELU) -> final reduce
  dp_split<<<dim3(DHN / 64, 32), blk, 0, stream>>>(H4, dp1W, P1, DD, DHN);
  dp_split2g<<<dim3(DINN / 64, 32), blk, 0, stream>>>(P1, dp1b, dp2W, P2, DHN, DINN);
  dp_reduce<0><<<dim3(DINN / 256, NB), blk, 0, stream>>>(P2, dp2b, Z, DINN);
}

// Round 14
// 159.190 us; speedup vs baseline: 1.6257x; 1.0098x over previous
//
#include <hip/hip_runtime.h>
#include <hip/hip_bf16.h>
#include <math.h>

#define NB 8        // batch
#define LNN 64      // nodes
#define LTN 256     // text len
#define DD 1024     // model dim
#define NH 4        // heads (each full width D)
#define HDD 4096    // NH*DD
#define DINN 2048
#define DHN 1024    // DIN/2

// 2*log2(e): tanh(x) = 1 - 2/(exp2(x*C)+1)
#define C_TANH 2.8853900817779268f

typedef __bf16 bf16x8 __attribute__((ext_vector_type(8)));
typedef float f32x4 __attribute__((ext_vector_type(4)));

__device__ __forceinline__ ushort f2b(float f) {
  unsigned int u = __builtin_bit_cast(unsigned int, f);
  u = (u + 0x7FFFu + ((u >> 16) & 1u)) >> 16;
  return (ushort)u;
}

// ---------------- mega-prep: activations cvt + all 6 weight transposes, 1 launch ----------------
__global__ __launch_bounds__(256) void prep(const float* __restrict__ node,
                                            ushort* __restrict__ node_bf,
                                            const float* __restrict__ text,
                                            ushort* __restrict__ text_bf,
                                            const float* __restrict__ Wq,
                                            const float* __restrict__ Wk,
                                            const float* __restrict__ Wv,
                                            const float* __restrict__ Wo,
                                            const float* __restrict__ aqW,
                                            const float* __restrict__ akW,
                                            ushort* __restrict__ TwtQKV,
                                            ushort* __restrict__ TwtWo,
                                            ushort* __restrict__ TwtAQ) {
  int bid = blockIdx.x;
  int t = threadIdx.x;
  if (bid < 1280) {
    const float* in;
    ushort* out;
    int i;
    if (bid < 256) { in = node; out = node_bf; i = (bid * 256 + t) * 8; }
    else { in = text; out = text_bf; i = ((bid - 256) * 256 + t) * 8; }
    float4 a = *(const float4*)(in + i);
    float4 b = *(const float4*)(in + i + 4);
    ushort4 o0 = {f2b(a.x), f2b(a.y), f2b(a.z), f2b(a.w)};
    ushort4 o1 = {f2b(b.x), f2b(b.y), f2b(b.z), f2b(b.w)};
    *(ushort4*)(out + i) = o0;
    *(ushort4*)(out + i + 4) = o1;
    return;
  }
  bid -= 1280;
  const float* W;
  ushort* dst0;
  int K, N, tt;
  if (bid < 3072) {
    int z = bid >> 10;
    tt = bid & 1023;
    W = (z == 0) ? Wq : ((z == 1) ? Wk : Wv);
    dst0 = TwtQKV + (size_t)z * DD * HDD;
    K = DD; N = HDD;
  } else if (bid < 4096) {
    tt = bid - 3072; W = Wo; dst0 = TwtWo; K = HDD; N = DD;
  } else if (bid < 4352) {
    tt = bid - 4096; W = aqW; dst0 = TwtAQ; K = DD; N = DD;
  } else {
    tt = bid - 4352; W = akW; dst0 = TwtAQ + (size_t)DD * DD; K = DD; N = DD;
  }
  int ntn = N >> 6;
  int n0 = (tt % ntn) << 6, k0 = (tt / ntn) << 6;
  __shared__ float tf[64][65];
  int r = t >> 2, c4 = (t & 3) * 16;
  const float* src = W + (size_t)(k0 + r) * N + n0 + c4;
  float4 v0 = *(const float4*)(src);
  float4 v1 = *(const float4*)(src + 4);
  float4 v2 = *(const float4*)(src + 8);
  float4 v3 = *(const float4*)(src + 12);
  *(float4*)&tf[r][c4] = v0;
  *(float4*)&tf[r][c4 + 4] = v1;
  *(float4*)&tf[r][c4 + 8] = v2;
  *(float4*)&tf[r][c4 + 12] = v3;
  __syncthreads();
  int nl = t >> 2, kc = (t & 3) * 16;
  ushort tmp[16];
#pragma unroll
  for (int j = 0; j < 16; ++j) tmp[j] = f2b(tf[kc + j][nl]);
  ushort* dst = dst0 + (size_t)(n0 + nl) * K + k0 + kc;
  *(uint4*)(dst) = *(uint4*)&tmp[0];
  *(uint4*)(dst + 8) = *(uint4*)&tmp[8];
}

// ---------------- QKV gemm (3 via grid.z): 64x128 tile, bf16 out, +bias ----------------
__global__ __launch_bounds__(256) void gemm_qkv3(const ushort* __restrict__ A,
                                                 const ushort* __restrict__ BtB,
                                                 const float* __restrict__ b0,
                                                 const float* __restrict__ b1,
                                                 const float* __restrict__ b2,
                                                 ushort* __restrict__ o0,
                                                 ushort* __restrict__ o1,
                                                 ushort* __restrict__ o2,
                                                 int M, int N, int K) {
  int z = blockIdx.z;
  const ushort* Bt = BtB + (size_t)z * N * K;
  const float* bias = (z == 0) ? b0 : ((z == 1) ? b1 : b2);
  ushort* Cout = (z == 0) ? o0 : ((z == 1) ? o1 : o2);
  __shared__ ushort Als[64 * 64];
  __shared__ ushort Bls[128 * 64];
  int tid = threadIdx.x;
  int m0 = blockIdx.y << 6, n0 = blockIdx.x << 7;
  int srow = tid >> 3, su = tid & 7;
  int sx = (su ^ (srow & 7)) * 8;
  const ushort* ga = A + (size_t)(m0 + srow) * K + su * 8;
  const ushort* gb = Bt + (size_t)(n0 + srow) * K + su * 8;
  int wa0 = srow * 64 + sx, wa1 = (srow + 32) * 64 + sx;
  int wb2 = (srow + 64) * 64 + sx, wb3 = (srow + 96) * 64 + sx;
  const size_t rs32 = (size_t)32 * K;
  int lane = tid & 63, w = tid >> 6;
  int wm = w >> 1, wn = w & 1;
  int r = lane & 15, kg = lane >> 4;
  f32x4 acc[2][4] = {};
  uint4 pa0 = *(const uint4*)(ga);
  uint4 pa1 = *(const uint4*)(ga + rs32);
  uint4 pb0 = *(const uint4*)(gb);
  uint4 pb1 = *(const uint4*)(gb + rs32);
  uint4 pb2 = *(const uint4*)(gb + 2 * rs32);
  uint4 pb3 = *(const uint4*)(gb + 3 * rs32);
  for (int k0 = 0; k0 < K; k0 += 64) {
    __syncthreads();
    *(uint4*)&Als[wa0] = pa0; *(uint4*)&Als[wa1] = pa1;
    *(uint4*)&Bls[wa0] = pb0; *(uint4*)&Bls[wa1] = pb1;
    *(uint4*)&Bls[wb2] = pb2; *(uint4*)&Bls[wb3] = pb3;
    __syncthreads();
    int kn = k0 + 64;
    if (kn < K) {
      pa0 = *(const uint4*)(ga + kn);
      pa1 = *(const uint4*)(ga + rs32 + kn);
      pb0 = *(const uint4*)(gb + kn);
      pb1 = *(const uint4*)(gb + rs32 + kn);
      pb2 = *(const uint4*)(gb + 2 * rs32 + kn);
      pb3 = *(const uint4*)(gb + 3 * rs32 + kn);
    }
#pragma unroll
    for (int h = 0; h < 2; ++h) {
      int sa = ((h * 4 + kg) ^ (r & 7)) * 8;
      bf16x8 af[2], bfr[4];
#pragma unroll
      for (int m = 0; m < 2; ++m)
        af[m] = *(const bf16x8*)&Als[(wm * 32 + m * 16 + r) * 64 + sa];
#pragma unroll
      for (int n = 0; n < 4; ++n)
        bfr[n] = *(const bf16x8*)&Bls[(wn * 64 + n * 16 + r) * 64 + sa];
#pragma unroll
      for (int m = 0; m < 2; ++m)
#pragma unroll
        for (int n = 0; n < 4; ++n)
          acc[m][n] = __builtin_amdgcn_mfma_f32_16x16x32_bf16(af[m], bfr[n], acc[m][n], 0, 0, 0);
    }
  }
#pragma unroll
  for (int m = 0; m < 2; ++m)
#pragma unroll
    for (int n = 0; n < 4; ++n) {
      f32x4 a = acc[m][n];
#pragma unroll
      for (int v = 0; v < 4; ++v) {
        int row = m0 + wm * 32 + m * 16 + kg * 4 + v;
        int col = n0 + wn * 64 + n * 16 + r;
        Cout[(size_t)row * N + col] = f2b(a[v] + bias[col]);
      }
    }
}

// ---------------- combined Wo split-K + ak gemm (flat grid 512) ----------------
// bid < 256: Wo partials (n=bid&7, m=(bid>>3)&7, ks=bid>>6), A=AO K=4096 Ks=1024.
// bid >= 256: ak (n=bid2&7, mt=bid2>>3 of 32), A=text_bf K=1024, out KAB*C_TANH (+akb+attb).
__global__ __launch_bounds__(256) void gemm_wo_ak(const ushort* __restrict__ AO,
                                                  const ushort* __restrict__ TwtWo,
                                                  const ushort* __restrict__ Tbf,
                                                  const ushort* __restrict__ TwtAK,
                                                  const float* __restrict__ akb,
                                                  const float* __restrict__ attb,
                                                  float* __restrict__ P_Wo,
                                                  float* __restrict__ KAB) {
  int bid = blockIdx.x;
  bool isWo = bid < 256;
  const ushort* Abase;
  const ushort* Bt;
  int m0, n0, K, Ks, kbase, N;
  if (isWo) {
    n0 = (bid & 7) << 7;
    m0 = ((bid >> 3) & 7) << 6;
    int ks = bid >> 6;
    K = HDD; Ks = HDD >> 2; kbase = ks * Ks;
    Abase = AO; Bt = TwtWo; N = DD;
  } else {
    int b2 = bid - 256;
    n0 = (b2 & 7) << 7;
    m0 = (b2 >> 3) << 6;
    K = DD; Ks = DD; kbase = 0;
    Abase = Tbf; Bt = TwtAK; N = DD;
  }
  __shared__ ushort Als[64 * 64];
  __shared__ ushort Bls[128 * 64];
  int tid = threadIdx.x;
  int srow = tid >> 3, su = tid & 7;
  int sx = (su ^ (srow & 7)) * 8;
  const ushort* ga = Abase + (size_t)(m0 + srow) * K + kbase + su * 8;
  const ushort* gb = Bt + (size_t)(n0 + srow) * K + kbase + su * 8;
  int wa0 = srow * 64 + sx, wa1 = (srow + 32) * 64 + sx;
  int wb2 = (srow + 64) * 64 + sx, wb3 = (srow + 96) * 64 + sx;
  const size_t rs32 = (size_t)32 * K;
  int lane = tid & 63, w = tid >> 6;
  int wm = w >> 1, wn = w & 1;
  int r = lane & 15, kg = lane >> 4;
  f32x4 acc[2][4] = {};
  uint4 pa0 = *(const uint4*)(ga);
  uint4 pa1 = *(const uint4*)(ga + rs32);
  uint4 pb0 = *(const uint4*)(gb);
  uint4 pb1 = *(const uint4*)(gb + rs32);
  uint4 pb2 = *(const uint4*)(gb + 2 * rs32);
  uint4 pb3 = *(const uint4*)(gb + 3 * rs32);
  for (int k0 = 0; k0 < Ks; k0 += 64) {
    __syncthreads();
    *(uint4*)&Als[wa0] = pa0; *(uint4*)&Als[wa1] = pa1;
    *(uint4*)&Bls[wa0] = pb0; *(uint4*)&Bls[wa1] = pb1;
    *(uint4*)&Bls[wb2] = pb2; *(uint4*)&Bls[wb3] = pb3;
    __syncthreads();
    int kn = k0 + 64;
    if (kn < Ks) {
      pa0 = *(const uint4*)(ga + kn);
      pa1 = *(const uint4*)(ga + rs32 + kn);
      pb0 = *(const uint4*)(gb + kn);
      pb1 = *(const uint4*)(gb + rs32 + kn);
      pb2 = *(const uint4*)(gb + 2 * rs32 + kn);
      pb3 = *(const uint4*)(gb + 3 * rs32 + kn);
    }
#pragma unroll
    for (int h = 0; h < 2; ++h) {
      int sa = ((h * 4 + kg) ^ (r & 7)) * 8;
      bf16x8 af[2], bfr[4];
#pragma unroll
      for (int m = 0; m < 2; ++m)
        af[m] = *(const bf16x8*)&Als[(wm * 32 + m * 16 + r) * 64 + sa];
#pragma unroll
      for (int n = 0; n < 4; ++n)
        bfr[n] = *(const bf16x8*)&Bls[(wn * 64 + n * 16 + r) * 64 + sa];
#pragma unroll
      for (int m = 0; m < 2; ++m)
#pragma unroll
        for (int n = 0; n < 4; ++n)
          acc[m][n] = __builtin_amdgcn_mfma_f32_16x16x32_bf16(af[m], bfr[n], acc[m][n], 0, 0, 0);
    }
  }
  if (isWo) {
    int ks = bid >> 6;
#pragma unroll
    for (int m = 0; m < 2; ++m)
#pragma unroll
      for (int n = 0; n < 4; ++n) {
        f32x4 a = acc[m][n];
#pragma unroll
        for (int v = 0; v < 4; ++v) {
          int row = m0 + wm * 32 + m * 16 + kg * 4 + v;
          int col = n0 + wn * 64 + n * 16 + r;
          P_Wo[((size_t)ks * 512 + row) * DD + col] = a[v];
        }
      }
  } else {
#pragma unroll
    for (int m = 0; m < 2; ++m)
#pragma unroll
      for (int n = 0; n < 4; ++n) {
        f32x4 a = acc[m][n];
#pragma unroll
        for (int v = 0; v < 4; ++v) {
          int row = m0 + wm * 32 + m * 16 + kg * 4 + v;
          int col = n0 + wn * 64 + n * 16 + r;
          KAB[(size_t)row * DD + col] = (a[v] + akb[col] + attb[col]) * C_TANH;
        }
      }
  }
}

// ---------------- aq gemm: H2 @ aqW, 64x128 tile, fp32 out *C_TANH ----------------
__global__ __launch_bounds__(256) void gemm_aq(const ushort* __restrict__ H2,
                                               const ushort* __restrict__ TwtAQ,
                                               const float* __restrict__ aqb,
                                               float* __restrict__ QBu,
                                               int M, int N, int K) {
  __shared__ ushort Als[64 * 64];
  __shared__ ushort Bls[128 * 64];
  int tid = threadIdx.x;
  int m0 = blockIdx.y << 6, n0 = blockIdx.x << 7;
  int srow = tid >> 3, su = tid & 7;
  int sx = (su ^ (srow & 7)) * 8;
  const ushort* ga = H2 + (size_t)(m0 + srow) * K + su * 8;
  const ushort* gb = TwtAQ + (size_t)(n0 + srow) * K + su * 8;
  int wa0 = srow * 64 + sx, wa1 = (srow + 32) * 64 + sx;
  int wb2 = (srow + 64) * 64 + sx, wb3 = (srow + 96) * 64 + sx;
  const size_t rs32 = (size_t)32 * K;
  int lane = tid & 63, w = tid >> 6;
  int wm = w >> 1, wn = w & 1;
  int r = lane & 15, kg = lane >> 4;
  f32x4 acc[2][4] = {};
  uint4 pa0 = *(const uint4*)(ga);
  uint4 pa1 = *(const uint4*)(ga + rs32);
  uint4 pb0 = *(const uint4*)(gb);
  uint4 pb1 = *(const uint4*)(gb + rs32);
  uint4 pb2 = *(const uint4*)(gb + 2 * rs32);
  uint4 pb3 = *(const uint4*)(gb + 3 * rs32);
  for (int k0 = 0; k0 < K; k0 += 64) {
    __syncthreads();
    *(uint4*)&Als[wa0] = pa0; *(uint4*)&Als[wa1] = pa1;
    *(uint4*)&Bls[wa0] = pb0; *(uint4*)&Bls[wa1] = pb1;
    *(uint4*)&Bls[wb2] = pb2; *(uint4*)&Bls[wb3] = pb3;
    __syncthreads();
    int kn = k0 + 64;
    if (kn < K) {
      pa0 = *(const uint4*)(ga + kn);
      pa1 = *(const uint4*)(ga + rs32 + kn);
      pb0 = *(const uint4*)(gb + kn);
      pb1 = *(const uint4*)(gb + rs32 + kn);
      pb2 = *(const uint4*)(gb + 2 * rs32 + kn);
      pb3 = *(const uint4*)(gb + 3 * rs32 + kn);
    }
#pragma unroll
    for (int h = 0; h < 2; ++h) {
      int sa = ((h * 4 + kg) ^ (r & 7)) * 8;
      bf16x8 af[2], bfr[4];
#pragma unroll
      for (int m = 0; m < 2; ++m)
        af[m] = *(const bf16x8*)&Als[(wm * 32 + m * 16 + r) * 64 + sa];
#pragma unroll
      for (int n = 0; n < 4; ++n)
        bfr[n] = *(const bf16x8*)&Bls[(wn * 64 + n * 16 + r) * 64 + sa];
#pragma unroll
      for (int m = 0; m < 2; ++m)
#pragma unroll
        for (int n = 0; n < 4; ++n)
          acc[m][n] = __builtin_amdgcn_mfma_f32_16x16x32_bf16(af[m], bfr[n], acc[m][n], 0, 0, 0);
    }
  }
#pragma unroll
  for (int m = 0; m < 2; ++m)
#pragma unroll
    for (int n = 0; n < 4; ++n) {
      f32x4 a = acc[m][n];
#pragma unroll
      for (int v = 0; v < 4; ++v) {
        int row = m0 + wm * 32 + m * 16 + kg * 4 + v;
        int col = n0 + wn * 64 + n * 16 + r;
        QBu[(size_t)row * N + col] = (a[v] + aqb[col]) * C_TANH;
      }
    }
}

// ---------------- Wo split-K(4) reduce + bias + residual + LayerNorm -> bf16 ----------------
__global__ __launch_bounds__(256) void wo_ln(const float* __restrict__ P,
                                             const float* __restrict__ bo,
                                             const float* __restrict__ node,
                                             const float* __restrict__ g,
                                             const float* __restrict__ be,
                                             ushort* __restrict__ Y) {
  int row = blockIdx.x, tid = threadIdx.x;
  int c = tid * 4;
  const size_t MN = (size_t)512 * 1024;
  size_t o = (size_t)row * DD + c;
  float4 v0 = *(const float4*)(P + o);
  float4 v1 = *(const float4*)(P + MN + o);
  float4 v2 = *(const float4*)(P + 2 * MN + o);
  float4 v3 = *(const float4*)(P + 3 * MN + o);
  float4 rv = *(const float4*)(node + o);
  float4 bv = *(const float4*)(bo + c);
  float4 v;
  v.x = v0.x + v1.x + v2.x + v3.x + rv.x + bv.x;
  v.y = v0.y + v1.y + v2.y + v3.y + rv.y + bv.y;
  v.z = v0.z + v1.z + v2.z + v3.z + rv.z + bv.z;
  v.w = v0.w + v1.w + v2.w + v3.w + rv.w + bv.w;
  float s = v.x + v.y + v.z + v.w;
  float ss = v.x * v.x + v.y * v.y + v.z * v.z + v.w * v.w;
  for (int o2 = 32; o2; o2 >>= 1) {
    s += __shfl_xor(s, o2, 64);
    ss += __shfl_xor(ss, o2, 64);
  }
  __shared__ float rb_[8];
  int lane = tid & 63, w = tid >> 6;
  if (lane == 0) { rb_[w] = s; rb_[4 + w] = ss; }
  __syncthreads();
  s = rb_[0] + rb_[1] + rb_[2] + rb_[3];
  ss = rb_[4] + rb_[5] + rb_[6] + rb_[7];
  float mu = s * (1.f / 1024.f);
  float var = ss * (1.f / 1024.f) - mu * mu;
  float rstd = rsqrtf(var + 1e-5f);
  ushort4 o4;
  o4.x = f2b((v.x - mu) * rstd * g[c + 0] + be[c + 0]);
  o4.y = f2b((v.y - mu) * rstd * g[c + 1] + be[c + 1]);
  o4.z = f2b((v.z - mu) * rstd * g[c + 2] + be[c + 2]);
  o4.w = f2b((v.w - mu) * rstd * g[c + 3] + be[c + 3]);
  *(ushort4*)(Y + (size_t)row * DD + c) = o4;
}

// ---------------- fused attention: per (bh, dtile) full QK^T + softmax + PV ----------------
__global__ __launch_bounds__(256) void attn_one(const ushort* __restrict__ Qb,
                                                const ushort* __restrict__ Kb,
                                                const ushort* __restrict__ Vb,
                                                const int* __restrict__ gmask,
                                                ushort* __restrict__ AO) {
  int bid = blockIdx.x;
  int bh = bid >> 3, dt = bid & 7;
  int b = bh >> 2;
  int d0 = dt * 128;
  size_t base = ((size_t)b * LNN) * HDD + (size_t)(bh & 3) * DD;
  __shared__ ushort Als[64 * 64];
  __shared__ ushort Bls[64 * 64];
  __shared__ float S[64][68];
  __shared__ ushort Pls[64 * 72];
  __shared__ ushort Vt[128 * 72];
  int tid = threadIdx.x;
  int lane = tid & 63, w = tid >> 6;
  int wm = w >> 1, wn = w & 1;
  int r = lane & 15, kg = lane >> 4;
  {
    int srow = tid >> 2, su0 = (tid & 3) * 2;
    const ushort* ga = Qb + base + (size_t)srow * HDD + su0 * 8;
    const ushort* gb = Kb + base + (size_t)srow * HDD + su0 * 8;
    int wa0 = srow * 64 + ((su0) ^ (srow & 7)) * 8;
    int wa1 = srow * 64 + ((su0 + 1) ^ (srow & 7)) * 8;
    f32x4 acc[2][2] = {};
    uint4 pa0 = *(const uint4*)(ga);
    uint4 pa1 = *(const uint4*)(ga + 8);
    uint4 pb0 = *(const uint4*)(gb);
    uint4 pb1 = *(const uint4*)(gb + 8);
    for (int k0 = 0; k0 < DD; k0 += 64) {
      __syncthreads();
      *(uint4*)&Als[wa0] = pa0; *(uint4*)&Als[wa1] = pa1;
      *(uint4*)&Bls[wa0] = pb0; *(uint4*)&Bls[wa1] = pb1;
      __syncthreads();
      int kn = k0 + 64;
      if (kn < DD) {
        pa0 = *(const uint4*)(ga + kn);
        pa1 = *(const uint4*)(ga + kn + 8);
        pb0 = *(const uint4*)(gb + kn);
        pb1 = *(const uint4*)(gb + kn + 8);
      }
#pragma unroll
      for (int h = 0; h < 2; ++h) {
        int sa = ((h * 4 + kg) ^ (r & 7)) * 8;
        bf16x8 af[2], bfr[2];
#pragma unroll
        for (int m = 0; m < 2; ++m)
          af[m] = *(const bf16x8*)&Als[(wm * 32 + m * 16 + r) * 64 + sa];
#pragma unroll
        for (int n = 0; n < 2; ++n)
          bfr[n] = *(const bf16x8*)&Bls[(wn * 32 + n * 16 + r) * 64 + sa];
#pragma unroll
        for (int m = 0; m < 2; ++m)
#pragma unroll
          for (int n = 0; n < 2; ++n)
            acc[m][n] = __builtin_amdgcn_mfma_f32_16x16x32_bf16(af[m], bfr[n], acc[m][n], 0, 0, 0);
      }
    }
#pragma unroll
    for (int m = 0; m < 2; ++m)
#pragma unroll
      for (int n = 0; n < 2; ++n)
#pragma unroll
        for (int v = 0; v < 4; ++v)
          S[wm * 32 + m * 16 + kg * 4 + v][wn * 32 + n * 16 + r] = acc[m][n][v];
  }
  {
    int kq = lane, dq = w * 32;
    const ushort* src = Vb + base + (size_t)kq * HDD + d0 + dq;
    uint4 v0 = *(const uint4*)src;
    uint4 v1 = *(const uint4*)(src + 8);
    uint4 v2 = *(const uint4*)(src + 16);
    uint4 v3 = *(const uint4*)(src + 24);
    ushort tmp[32];
    *(uint4*)&tmp[0] = v0; *(uint4*)&tmp[8] = v1;
    *(uint4*)&tmp[16] = v2; *(uint4*)&tmp[24] = v3;
#pragma unroll
    for (int j = 0; j < 32; ++j) Vt[(dq + j) * 72 + kq] = tmp[j];
  }
  __syncthreads();
  bool valid = gmask[b * LNN + lane] != 0;
  for (int i = 0; i < 16; ++i) {
    int q = w * 16 + i;
    float v = valid ? S[q][lane] * 0.03125f : -__builtin_inff();
    float mx = v;
    for (int o = 32; o; o >>= 1) mx = fmaxf(mx, __shfl_xor(mx, o, 64));
    float e = valid ? __expf(v - mx) : 0.f;
    float s = e;
    for (int o = 32; o; o >>= 1) s += __shfl_xor(s, o, 64);
    Pls[q * 72 + lane] = f2b(__fdividef(e, s));
  }
  __syncthreads();
  f32x4 acc[2][4] = {};
#pragma unroll
  for (int h = 0; h < 2; ++h) {
    int ko = h * 32 + kg * 8;
    bf16x8 af[2], bfr[4];
#pragma unroll
    for (int m = 0; m < 2; ++m)
      af[m] = *(const bf16x8*)&Pls[(wm * 32 + m * 16 + r) * 72 + ko];
#pragma unroll
    for (int n = 0; n < 4; ++n)
      bfr[n] = *(const bf16x8*)&Vt[(wn * 64 + n * 16 + r) * 72 + ko];
#pragma unroll
    for (int m = 0; m < 2; ++m)
#pragma unroll
      for (int n = 0; n < 4; ++n)
        acc[m][n] = __builtin_amdgcn_mfma_f32_16x16x32_bf16(af[m], bfr[n], acc[m][n], 0, 0, 0);
  }
#pragma unroll
  for (int m = 0; m < 2; ++m)
#pragma unroll
    for (int n = 0; n < 4; ++n) {
      f32x4 a = acc[m][n];
#pragma unroll
      for (int v = 0; v < 4; ++v) {
        int q = wm * 32 + m * 16 + kg * 4 + v;
        int col = wn * 64 + n * 16 + r;
        AO[base + (size_t)q * HDD + d0 + col] = f2b(a[v]);
      }
    }
}

// ---------------- additive attention phase 1: 8-q reuse, 128-d slices ----------------
__global__ __launch_bounds__(256) void addatt_e(const float* __restrict__ QBu,
                                                const float* __restrict__ KAB,
                                                const float* __restrict__ av_,
                                                float* __restrict__ E8) {
  int ds = blockIdx.x, qt = blockIdx.y, b = blockIdx.z;
  int tid = threadIdx.x;
  __shared__ float qs[8][128];
  __shared__ float avs[128];
  __shared__ float red[4];
  int bq0 = b * LNN + qt * 8;
  {
    int qq = tid >> 5, dd = (tid & 31) * 4;
    *(float4*)&qs[qq][dd] = *(const float4*)(QBu + (size_t)(bq0 + qq) * DD + ds * 128 + dd);
  }
  float av = (tid < 128) ? av_[ds * 128 + tid] : 0.f;
  if (tid < 128) avs[tid] = av;
  float s = av;
  for (int o = 32; o; o >>= 1) s += __shfl_xor(s, o, 64);
  int lane = tid & 63, w = tid >> 6;
  if (lane == 0) red[w] = s;
  __syncthreads();
  float sumav = red[0] + red[1] + red[2] + red[3];
  const float* kr = KAB + (size_t)(b * LTN + tid) * DD + ds * 128;
  float ac[8] = {};
#pragma unroll 2
  for (int d = 0; d < 128; d += 4) {
    float4 kv = *(const float4*)(kr + d);
    float4 av4 = *(const float4*)&avs[d];
#pragma unroll
    for (int qq = 0; qq < 8; ++qq) {
      float4 q4 = *(const float4*)&qs[qq][d];
      ac[qq] = fmaf(av4.x, __builtin_amdgcn_rcpf(__builtin_amdgcn_exp2f(q4.x + kv.x) + 1.f), ac[qq]);
      ac[qq] = fmaf(av4.y, __builtin_amdgcn_rcpf(__builtin_amdgcn_exp2f(q4.y + kv.y) + 1.f), ac[qq]);
      ac[qq] = fmaf(av4.z, __builtin_amdgcn_rcpf(__builtin_amdgcn_exp2f(q4.z + kv.z) + 1.f), ac[qq]);
      ac[qq] = fmaf(av4.w, __builtin_amdgcn_rcpf(__builtin_amdgcn_exp2f(q4.w + kv.w) + 1.f), ac[qq]);
    }
  }
  size_t ebase = ((size_t)ds * 512 + bq0) * LTN + tid;
#pragma unroll
  for (int qq = 0; qq < 8; ++qq)
    E8[ebase + (size_t)qq * LTN] = sumav - 2.f * ac[qq];
}

// ---------------- additive attention phase 2: sum 8 partials + masked softmax ----------------
__global__ __launch_bounds__(256) void addatt_sm(const float* __restrict__ E8,
                                                 const int* __restrict__ lmask,
                                                 float* __restrict__ Wv) {
  int bq = blockIdx.x;
  int b = bq >> 6;
  int tid = threadIdx.x;
  __shared__ float rb_[8];
  float e = 0.f;
#pragma unroll
  for (int ks = 0; ks < 8; ++ks)
    e += E8[((size_t)ks * 512 + bq) * LTN + tid];
  bool valid = lmask[b * LTN + tid] != 0;
  float v = valid ? e : -__builtin_inff();
  int lane = tid & 63, w = tid >> 6;
  float m = v;
  for (int o = 32; o; o >>= 1) m = fmaxf(m, __shfl_xor(m, o, 64));
  if (lane == 0) rb_[w] = m;
  __syncthreads();
  m = fmaxf(fmaxf(rb_[0], rb_[1]), fmaxf(rb_[2], rb_[3]));
  float ex = valid ? __expf(v - m) : 0.f;
  float sm = ex;
  for (int o = 32; o; o >>= 1) sm += __shfl_xor(sm, o, 64);
  if (lane == 0) rb_[4 + w] = sm;
  __syncthreads();
  sm = rb_[4] + rb_[5] + rb_[6] + rb_[7];
  Wv[(size_t)bq * LTN + tid] = __fdividef(ex, sm);
}

// ---------------- additive attention phase 3: pooled context ----------------
__global__ __launch_bounds__(256) void addatt_pool(const float* __restrict__ Wv,
                                                   const float* __restrict__ text,
                                                   const int* __restrict__ gmask,
                                                   float* __restrict__ H4) {
  int dt = blockIdx.x, b = blockIdx.y;
  int tid = threadIdx.x;
  __shared__ float cf[LTN];
  float c = 0.f, cnt = 0.f;
#pragma unroll 8
  for (int q = 0; q < LNN; ++q) {
    float m = (gmask[b * LNN + q] != 0) ? 1.f : 0.f;
    cnt += m;
    c = fmaf(m, Wv[(size_t)(b * LNN + q) * LTN + tid], c);
  }
  cf[tid] = c;
  cnt = fmaxf(cnt, 9.765625e-04f);
  __syncthreads();
  int d = dt * 256 + tid;
  const float* tb = text + (size_t)b * LTN * DD + d;
  float acc = 0.f;
#pragma unroll 8
  for (int k = 0; k < LTN; ++k) acc = fmaf(cf[k], tb[(size_t)k * DD], acc);
  H4[b * DD + d] = acc / cnt;
}

// ---------------- split-K GEMV (dp1) ----------------
__global__ __launch_bounds__(256) void dp_split(const float* __restrict__ X,
                                                const float* __restrict__ W,
                                                float* __restrict__ P,
                                                int K, int N) {
  int jt = blockIdx.x, kt = blockIdx.y;
  int t = threadIdx.x;
  __shared__ float xs[8][32];
  if (t < 64) {
    int b = t >> 3, kk = (t & 7) * 4;
    *(float4*)&xs[b][kk] = *(const float4*)(X + (size_t)b * K + kt * 32 + kk);
  }
  __syncthreads();
  int j = jt * 64 + (t & 63);
  int bg = (t >> 6) * 2;
  const float* wp = W + (size_t)(kt * 32) * N + j;
  float a0 = 0.f, a1 = 0.f;
#pragma unroll
  for (int k = 0; k < 32; ++k) {
    float w = wp[(size_t)k * N];
    a0 = fmaf(xs[bg + 0][k], w, a0);
    a1 = fmaf(xs[bg + 1][k], w, a1);
  }
  P[((size_t)kt * 8 + bg + 0) * N + j] = a0;
  P[((size_t)kt * 8 + bg + 1) * N + j] = a1;
}

// ---------------- dp2 split-K GEMV with inline dp1-reduce + GELU ----------------
__global__ __launch_bounds__(256) void dp_split2g(const float* __restrict__ P1,
                                                  const float* __restrict__ b1,
                                                  const float* __restrict__ W,
                                                  float* __restrict__ P,
                                                  int K, int N) {
  int jt = blockIdx.x, kt = blockIdx.y;
  int t = threadIdx.x;
  __shared__ float xs[8][32];
  {
    int b = t >> 5, kk = t & 31;
    int j = kt * 32 + kk;
    float s = b1[j];
#pragma unroll 8
    for (int p = 0; p < 32; ++p) s += P1[((size_t)p * 8 + b) * K + j];
    xs[b][kk] = 0.5f * s * (1.f + erff(s * 0.70710678118654752440f));
  }
  __syncthreads();
  int j = jt * 64 + (t & 63);
  int bg = (t >> 6) * 2;
  const float* wp = W + (size_t)(kt * 32) * N + j;
  float a0 = 0.f, a1 = 0.f;
#pragma unroll
  for (int k = 0; k < 32; ++k) {
    float w = wp[(size_t)k * N];
    a0 = fmaf(xs[bg + 0][k], w, a0);
    a1 = fmaf(xs[bg + 1][k], w, a1);
  }
  P[((size_t)kt * 8 + bg + 0) * N + j] = a0;
  P[((size_t)kt * 8 + bg + 1) * N + j] = a1;
}

template <int GELU>
__global__ __launch_bounds__(256) void dp_reduce(const float* __restrict__ P,
                                                 const float* __restrict__ bias,
                                                 float* __restrict__ O, int N) {
  int b = blockIdx.y;
  int j = blockIdx.x * 256 + threadIdx.x;
  float s = bias[j];
#pragma unroll 8
  for (int kt = 0; kt < 32; ++kt) s += P[((size_t)kt * 8 + b) * N + j];
  if constexpr (GELU) s = 0.5f * s * (1.f + erff(s * 0.70710678118654752440f));
  O[(size_t)b * N + j] = s;
}

extern "C" void kernel_launch(void* const* d_in, const int* in_sizes, int n_in,
                              void* d_out, int out_size, void* d_ws, size_t ws_size,
                              hipStream_t stream) {
  const float* text = (const float*)d_in[0];
  const float* node = (const float*)d_in[1];
  const float* Wq = (const float*)d_in[2];
  const float* bq = (const float*)d_in[3];
  const float* Wk = (const float*)d_in[4];
  const float* bk = (const float*)d_in[5];
  const float* Wv = (const float*)d_in[6];
  const float* bv = (const float*)d_in[7];
  const float* Wo = (const float*)d_in[8];
  const float* bo = (const float*)d_in[9];
  const float* lng = (const float*)d_in[10];
  const float* lnb = (const float*)d_in[11];
  const float* aqW = (const float*)d_in[12];
  const float* aqb = (const float*)d_in[13];
  const float* akW = (const float*)d_in[14];
  const float* akb = (const float*)d_in[15];
  const float* attv = (const float*)d_in[16];
  const float* attb = (const float*)d_in[17];
  const float* dp1W = (const float*)d_in[18];
  const float* dp1b = (const float*)d_in[19];
  const float* dp2W = (const float*)d_in[20];
  const float* dp2b = (const float*)d_in[21];
  const int* gmask = (const int*)d_in[22];
  const int* lmask = (const int*)d_in[23];
  (void)in_sizes; (void)n_in; (void)out_size; (void)ws_size;

  char* base = (char*)d_ws;
#define MB(x) (((size_t)(x)) << 20)
  ushort* TwtQKV = (ushort*)(base);                 // 0..24 MB
  ushort* TwtWo = (ushort*)(base + MB(24));         // 24..32
  ushort* TwtAQ = (ushort*)(base + MB(32));         // 32..36 (aq 2MB + ak 2MB)
  ushort* node_bf = (ushort*)(base + MB(36));       // 36..37
  ushort* text_bf = (ushort*)(base + MB(37));       // 37..41
  ushort* Qb = (ushort*)(base + MB(41));            // 41..45
  ushort* Kb = (ushort*)(base + MB(45));            // 45..49
  ushort* Vb = (ushort*)(base + MB(49));            // 49..53
  ushort* AO = (ushort*)(base + MB(53));            // 53..57
  float* P_Wo = (float*)(base + MB(61));            // 61..69 (4 slices x 2MB)
  ushort* H2 = (ushort*)(base + MB(69));            // 69..70
  float* QBu = (float*)(base + MB(70));             // 70..72
  float* KAB = (float*)(base + MB(72));             // 72..80
  float* E8 = (float*)(base + MB(80));              // 80..84
  float* Wvb = (float*)(base + MB(84));             // 84..84.5
  float* H4 = (float*)(base + MB(84) + (512 << 10));   // 32KB
  float* P1 = (float*)(base + MB(85));              // 85..86
  float* P2 = (float*)(base + MB(86));              // 86..88
  float* Z = (float*)d_out;
#undef MB

  const int M1 = NB * LNN;  // 512
  dim3 blk(256);

  // one launch: activations cvt + all 6 weight transposes
  prep<<<dim3(5888), blk, 0, stream>>>(node, node_bf, text, text_bf,
                                       Wq, Wk, Wv, Wo, aqW, akW,
                                       TwtQKV, TwtWo, TwtAQ);

  // QKV projections (64x128 tiles, grid.z = 3)
  gemm_qkv3<<<dim3(HDD / 128, M1 / 64, 3), blk, 0, stream>>>(node_bf, TwtQKV, bq, bk, bv, Qb, Kb, Vb, M1, HDD, DD);

  // fused self-attention: QK^T (redundant per d-tile) + softmax + PV, 256 blocks
  attn_one<<<dim3(NB * NH * 8), blk, 0, stream>>>(Qb, Kb, Vb, gmask, AO);

  // Wo split-K partials + ak gemm co-scheduled in one 512-block launch
  gemm_wo_ak<<<dim3(512), blk, 0, stream>>>(AO, TwtWo, text_bf, TwtAQ + (size_t)DD * DD,
                                            akb, attb, P_Wo, KAB);
  wo_ln<<<dim3(M1), blk, 0, stream>>>(P_Wo, bo, node, lng, lnb, H2);

  // aq gemm (depends on H2), output pre-scaled by C_TANH
  gemm_aq<<<dim3(DD / 128, M1 / 64), blk, 0, stream>>>(H2, TwtAQ, aqb, QBu, M1, DD, DD);

  // additive attention: partial-e (8-q reuse, 8 d-slices) -> softmax -> pooled context
  addatt_e<<<dim3(8, 8, NB), blk, 0, stream>>>(QBu, KAB, attv, E8);
  addatt_sm<<<dim3(M1), blk, 0, stream>>>(E8, lmask, Wvb);
  addatt_pool<<<dim3(4, NB), blk, 0, stream>>>(Wvb, text, gmask, H4);

  // MLP: dp1 split -> (dp2 split with inline dp1-reduce+GELU) -> final reduce
  dp_split<<<dim3(DHN / 64, 32), blk, 0, stream>>>(H4, dp1W, P1, DD, DHN);
  dp_split2g<<<dim3(DINN / 64, 32), blk, 0, stream>>>(P1, dp1b, dp2W, P2, DHN, DINN);
  dp_reduce<0><<<dim3(DINN / 256, NB), blk, 0, stream>>>(P2, dp2b, Z, DINN);
}